// Round 8
// baseline (286.851 us; speedup 1.0000x reference)
//
#include <hip/hip_runtime.h>
#include <stdint.h>

constexpr int kHW = 16384;   // 128*128 pixels (grid shared across batch)
constexpr int kB  = 4;
constexpr int kM  = 256;     // tokens

typedef _Float16 half8 __attribute__((ext_vector_type(8)));  // 8 fp16 (4 VGPRs)
typedef __attribute__((ext_vector_type(4))) float f32x4;     // MFMA accum

// ---------------- helpers ----------------
__device__ __forceinline__ unsigned short f2h(float f) {
  _Float16 h = (_Float16)f;
  return __builtin_bit_cast(unsigned short, h);
}
__device__ __forceinline__ float h2f(unsigned short u) {
  return (float)__builtin_bit_cast(_Float16, u);
}

// ---------------- kernel 0: prep = wprep (64 blocks) + kv (1024 blocks), one launch ----------------
__global__ __launch_bounds__(256) void prep_kernel(
    const float* __restrict__ tokens, const float* __restrict__ tokvW,
    unsigned short* __restrict__ kn_ws, unsigned short* __restrict__ vt_ws,
    const float* __restrict__ tooW, const float* __restrict__ modW0,
    const float* __restrict__ modW1, const float* __restrict__ hvW0,
    const float* __restrict__ qW, const float* __restrict__ bwW0,
    const float* __restrict__ bwW1, const float* __restrict__ toqW,
    unsigned short* __restrict__ tooWt, unsigned short* __restrict__ modW0t,
    unsigned short* __restrict__ modW1t, unsigned short* __restrict__ hvW0t,
    unsigned short* __restrict__ qWt, unsigned short* __restrict__ bw0t,
    unsigned short* __restrict__ bw1t, unsigned short* __restrict__ toqWt)
{
  __shared__ __align__(16) float tok[256];
  int bx = blockIdx.x, tid = threadIdx.x;

  if (bx < kB * kM) {
    // ---- kv part ----
    int b = bx >> 8, j = bx & 255, c = tid;
    tok[c] = tokens[(b * kM + j) * 256 + c];
    __syncthreads();
    float acc = 0.f;
    for (int i4 = 0; i4 < 64; i4++) {
      float4 t4 = *(const float4*)&tok[i4 * 4];
      acc += t4.x * tokvW[(i4*4+0)*256 + c] + t4.y * tokvW[(i4*4+1)*256 + c]
           + t4.z * tokvW[(i4*4+2)*256 + c] + t4.w * tokvW[(i4*4+3)*256 + c];
    }
    unsigned short hv = f2h(acc);
    if (c < 128) {
      int h = c >> 6, dd = c & 63;
      kn_ws[((size_t)(b*2+h)*256 + j) * 64 + dd] = hv;
    } else {
      int c2 = c - 128;
      int h = c2 >> 6, dd = c2 & 63;
      vt_ws[((size_t)(b*2+h)*64 + dd) * 256 + j] = hv;
    }
  } else {
    // ---- wprep part: block t -> (matrix m, K-chunk ch of 8) ----
    int t = bx - kB * kM;          // 0..63
    int m = t >> 3, ch = t & 7;
    const float* Ws[8] = {tooW, modW0, modW1, hvW0, qW, bwW0, bwW1, toqW};
    unsigned short* Wts[8] = {tooWt, modW0t, modW1t, hvW0t, qWt, bw0t, bw1t, toqWt};
    const int Ks[8] = {128, 256, 256, 256, 64, 64, 64, 256};
    const int Ns[8] = {256, 256, 256, 256, 256, 256, 256, 128};
    const float* W = Ws[m];
    unsigned short* Wt = Wts[m];
    int K = Ks[m], N = Ns[m];
    int nkb = K / 8;               // 8, 16 or 32
    int per = nkb >> 3;            // 1, 2 or 4 iters per block
    int kb0 = ch * per;
    if (tid < N) {
      for (int kb = kb0; kb < kb0 + per; kb++) {
        unsigned short sv[8];
#pragma unroll
        for (int i = 0; i < 8; i++)
          sv[i] = f2h(W[(kb * 8 + i) * N + tid]);   // coalesced across tid
        *(uint4*)&Wt[tid * K + kb * 8] = *(const uint4*)sv;
      }
    }
  }
}

// ---------------- kernel 1: fused feat + attn, 32-px blocks (M=32, proven shapes) ----------------
constexpr int kAPitch = 264;   // xq / P_s pitch
constexpr int kQPitch = 136;   // qc pitch

__global__ __launch_bounds__(256, 2) void featattn_kernel(
    const float* __restrict__ coords,
    const float* __restrict__ Bq, const float* __restrict__ Bl0, const float* __restrict__ Bl1,
    const float* __restrict__ qb, const float* __restrict__ bwb0, const float* __restrict__ bwb1,
    const unsigned short* __restrict__ qWt, const unsigned short* __restrict__ bw0t,
    const unsigned short* __restrict__ bw1t, const unsigned short* __restrict__ toqWt,
    const unsigned short* __restrict__ kn_ws, const unsigned short* __restrict__ vt_ws,
    unsigned short* __restrict__ h0_hf, unsigned short* __restrict__ h1_hf,
    unsigned short* __restrict__ o_hf)
{
  __shared__ __align__(16) unsigned short arena[15360];
  __shared__ __align__(16) unsigned short qc_s[32 * kQPitch];
  __shared__ float t_s[32];
  __shared__ float coords_s[64];
  __shared__ float red_max[32][4];
  __shared__ float red_sum[32][4];

  unsigned short* ff  = arena;          // [3][32][72]
  unsigned short* xq  = arena + 6912;   // [32][264]
  unsigned short* P_s = arena;          // [32][264], after feat

  int tid = threadIdx.x;
  int px0 = blockIdx.x * 32;
  int w = tid >> 6, ln = tid & 63;
  int c = ln & 15, q = ln >> 4;

  const f32x4 zero4 = {0.f, 0.f, 0.f, 0.f};

  // ===== feat: Fourier features =====
  if (tid < 64) coords_s[tid] = coords[px0 * 2 + tid];
  __syncthreads();

#pragma unroll
  for (int r = 0; r < 24; r++) {
    int v = r * 256 + tid;
    int mat = v >> 11;
    int p = (v >> 6) & 31;
    int f = v & 63;
    int fr = f & 31;
    const float* Bm = (mat == 0) ? Bq : (mat == 1 ? Bl0 : Bl1);
    float x = coords_s[p * 2 + 0];
    float y = coords_s[p * 2 + 1];
    float proj = 6.283185307179586f * (x * Bm[fr*2+0] + y * Bm[fr*2+1]);
    float s, cc;
    __sincosf(proj, &s, &cc);
    ff[(mat * 32 + p) * 72 + f] = f2h((f < 32) ? cc : s);
  }
  if (tid < 32) {
    float x = coords_s[tid * 2 + 0];
    float y = coords_s[tid * 2 + 1];
    int row = min(max((int)(x * 16.0f), 0), 15);
    int col = min(max((int)(y * 16.0f), 0), 15);
    t_s[tid] = (float)(row * 16 + col) * (1.0f / 256.0f);
  }
  __syncthreads();

  // ===== feat: 3 GEMMs M=32, N=256, K=64 =====
  for (int mat = 0; mat < 3; mat++) {
    const unsigned short* Wt = (mat == 0) ? qWt : (mat == 1 ? bw0t : bw1t);
    const float* bias = (mat == 0) ? qb : (mat == 1 ? bwb0 : bwb1);
    f32x4 acc[8];
#pragma unroll
    for (int i = 0; i < 8; i++) acc[i] = zero4;
#pragma unroll
    for (int ks = 0; ks < 2; ks++) {
      int koff = ks * 32 + q * 8;
      half8 bfr[4];
#pragma unroll
      for (int nt = 0; nt < 4; nt++)
        bfr[nt] = *(const half8*)(Wt + (size_t)(w*64 + nt*16 + c) * 64 + koff);
      half8 afr[2];
#pragma unroll
      for (int mt = 0; mt < 2; mt++)
        afr[mt] = *(const half8*)(ff + (mat * 32 + mt*16 + c) * 72 + koff);
#pragma unroll
      for (int mt = 0; mt < 2; mt++)
#pragma unroll
        for (int nt = 0; nt < 4; nt++)
          acc[mt*4+nt] = __builtin_amdgcn_mfma_f32_16x16x32_f16(afr[mt], bfr[nt], acc[mt*4+nt], 0, 0, 0);
    }
    float bv[4];
#pragma unroll
    for (int nt = 0; nt < 4; nt++) bv[nt] = bias[w*64 + nt*16 + c];
#pragma unroll
    for (int mt = 0; mt < 2; mt++)
#pragma unroll
      for (int nt = 0; nt < 4; nt++)
#pragma unroll
        for (int rg = 0; rg < 4; rg++) {
          int row = mt*16 + q*4 + rg, col = w*64 + nt*16 + c;
          unsigned short hv = f2h(fmaxf(acc[mt*4+nt][rg] + bv[nt], 0.f));
          if (mat == 0)      xq[row * kAPitch + col] = hv;
          else if (mat == 1) h0_hf[((size_t)(px0 + row)) * 256 + col] = hv;
          else               h1_hf[((size_t)(px0 + row)) * 256 + col] = hv;
        }
  }
  __syncthreads();   // xq ready

  // ===== feat: q GEMM M=32, N=128, K=256 -> qc_s =====
  {
    f32x4 acc2[4];
#pragma unroll
    for (int i = 0; i < 4; i++) acc2[i] = zero4;
#pragma unroll
    for (int kt = 0; kt < 8; kt++) {
      int koff = kt * 32 + q * 8;
      half8 bfr[2];
#pragma unroll
      for (int nt = 0; nt < 2; nt++)
        bfr[nt] = *(const half8*)(toqWt + (size_t)(w*32 + nt*16 + c) * 256 + koff);
      half8 afr[2];
#pragma unroll
      for (int mt = 0; mt < 2; mt++)
        afr[mt] = *(const half8*)(xq + (mt*16 + c) * kAPitch + koff);
#pragma unroll
      for (int mt = 0; mt < 2; mt++)
#pragma unroll
        for (int nt = 0; nt < 2; nt++)
          acc2[mt*2+nt] = __builtin_amdgcn_mfma_f32_16x16x32_f16(afr[mt], bfr[nt], acc2[mt*2+nt], 0, 0, 0);
    }
#pragma unroll
    for (int mt = 0; mt < 2; mt++)
#pragma unroll
      for (int nt = 0; nt < 2; nt++)
#pragma unroll
        for (int rg = 0; rg < 4; rg++) {
          int row = mt*16 + q*4 + rg, col = w*32 + nt*16 + c;
          qc_s[row * kQPitch + col] = f2h(acc2[mt*2+nt][rg]);
        }
  }

  // ===== attn: loop over batch & head; qc stays in LDS =====
  for (int b = 0; b < kB; b++) {
    for (int h = 0; h < 2; h++) {
      __syncthreads();   // qc visible; previous P_s reads done

      // QK^T: M=32, N=256 (wave strip of 64), K=64
      f32x4 acc[8];
#pragma unroll
      for (int i = 0; i < 8; i++) acc[i] = zero4;
      const unsigned short* kbase = kn_ws + (size_t)(b*2+h) * 256 * 64;
#pragma unroll
      for (int ks = 0; ks < 2; ks++) {
        int koff = ks * 32 + q * 8;
        half8 a0 = *(const half8*)(qc_s + c * kQPitch + h*64 + koff);
        half8 a1 = *(const half8*)(qc_s + (16 + c) * kQPitch + h*64 + koff);
#pragma unroll
        for (int nt = 0; nt < 4; nt++) {
          half8 bf = *(const half8*)(kbase + (size_t)(w*64 + nt*16 + c) * 64 + koff);
          acc[0*4+nt] = __builtin_amdgcn_mfma_f32_16x16x32_f16(a0, bf, acc[0*4+nt], 0, 0, 0);
          acc[1*4+nt] = __builtin_amdgcn_mfma_f32_16x16x32_f16(a1, bf, acc[1*4+nt], 0, 0, 0);
        }
      }

      // bias + scale, row max
      float lm[2][4];
#pragma unroll
      for (int mt = 0; mt < 2; mt++)
#pragma unroll
        for (int rg = 0; rg < 4; rg++) {
          int row = mt*16 + q*4 + rg;
          float tv = t_s[row];
          float mx = -1e30f;
#pragma unroll
          for (int nt = 0; nt < 4; nt++) {
            int token = w*64 + nt*16 + c;
            float pos = ((float)token + 0.5f) * (1.0f / 256.0f);
            float db = tv - pos;
            float sb = acc[mt*4+nt][rg] * 0.125f - 10.0f * db * db;
            acc[mt*4+nt][rg] = sb;
            mx = fmaxf(mx, sb);
          }
          lm[mt][rg] = mx;
        }
#pragma unroll
      for (int s = 1; s < 16; s <<= 1)
#pragma unroll
        for (int mt = 0; mt < 2; mt++)
#pragma unroll
          for (int rg = 0; rg < 4; rg++)
            lm[mt][rg] = fmaxf(lm[mt][rg], __shfl_xor(lm[mt][rg], s, 64));
      if (c == 0) {
#pragma unroll
        for (int mt = 0; mt < 2; mt++)
#pragma unroll
          for (int rg = 0; rg < 4; rg++)
            red_max[mt*16 + q*4 + rg][w] = lm[mt][rg];
      }
      __syncthreads();

      // exp -> P_s, partial sums
      float ps[2][4];
#pragma unroll
      for (int mt = 0; mt < 2; mt++)
#pragma unroll
        for (int rg = 0; rg < 4; rg++) {
          int row = mt*16 + q*4 + rg;
          float gm = fmaxf(fmaxf(red_max[row][0], red_max[row][1]),
                           fmaxf(red_max[row][2], red_max[row][3]));
          float sum = 0.f;
#pragma unroll
          for (int nt = 0; nt < 4; nt++) {
            float e = __expf(acc[mt*4+nt][rg] - gm);
            sum += e;
            P_s[row * kAPitch + w*64 + nt*16 + c] = f2h(e);
          }
          ps[mt][rg] = sum;
        }
#pragma unroll
      for (int s = 1; s < 16; s <<= 1)
#pragma unroll
        for (int mt = 0; mt < 2; mt++)
#pragma unroll
          for (int rg = 0; rg < 4; rg++)
            ps[mt][rg] += __shfl_xor(ps[mt][rg], s, 64);
      if (c == 0) {
#pragma unroll
        for (int mt = 0; mt < 2; mt++)
#pragma unroll
          for (int rg = 0; rg < 4; rg++)
            red_sum[mt*16 + q*4 + rg][w] = ps[mt][rg];
      }
      __syncthreads();

      // PV: wave w -> dh cols [w*16, w*16+16), K=256
      f32x4 oacc[2] = {zero4, zero4};
      const unsigned short* vbase = vt_ws + (size_t)(b*2+h) * 64 * 256;
#pragma unroll
      for (int kt = 0; kt < 8; kt++) {
        int koff = kt * 32 + q * 8;
        half8 bf = *(const half8*)(vbase + (size_t)(w*16 + c) * 256 + koff);
        half8 a0 = *(const half8*)(P_s + (0*16 + c) * kAPitch + koff);
        half8 a1 = *(const half8*)(P_s + (1*16 + c) * kAPitch + koff);
        oacc[0] = __builtin_amdgcn_mfma_f32_16x16x32_f16(a0, bf, oacc[0], 0, 0, 0);
        oacc[1] = __builtin_amdgcn_mfma_f32_16x16x32_f16(a1, bf, oacc[1], 0, 0, 0);
      }
#pragma unroll
      for (int mt = 0; mt < 2; mt++)
#pragma unroll
        for (int rg = 0; rg < 4; rg++) {
          int row = mt*16 + q*4 + rg;
          float rinv = 1.0f / (red_sum[row][0] + red_sum[row][1] +
                               red_sum[row][2] + red_sum[row][3]);
          o_hf[((size_t)(b * kHW + px0 + row)) * 128 + h*64 + w*16 + c] =
              f2h(oacc[mt][rg] * rinv);
        }
    }
  }
}

// ---------------- kernel 2: MFMA MLP chain, fp16, M=32 rows (8 px x 4 batch) ----------------
// R6 structure (m0 via LDS -- the no-spill configuration) at half the M:
// LDS 40KB -> 4 blocks/CU (16 waves, 4/SIMD). Independent blocks desync across
// barriers -> a block's vmcnt/barrier drain overlaps other blocks' MFMA.
constexpr int kPitch = 264;   // fp16 LDS pitch

template <int KD>
__device__ __forceinline__ void gemm2m(
    const unsigned short* abuf, const unsigned short* wt,
    f32x4* acc /*[2*4]*/, int c, int q)
{
#pragma unroll
  for (int ks = 0; ks < KD / 32; ks++) {
    int koff = ks * 32 + q * 8;
    half8 bfr[4];
#pragma unroll
    for (int nt = 0; nt < 4; nt++)
      bfr[nt] = *(const half8*)(wt + (nt * 16 + c) * KD + koff);
    half8 afr[2];
#pragma unroll
    for (int mt = 0; mt < 2; mt++)
      afr[mt] = *(const half8*)(abuf + (mt * 16 + c) * kPitch + koff);
#pragma unroll
    for (int mt = 0; mt < 2; mt++)
#pragma unroll
      for (int nt = 0; nt < 4; nt++)
        acc[mt * 4 + nt] = __builtin_amdgcn_mfma_f32_16x16x32_f16(afr[mt], bfr[nt], acc[mt * 4 + nt], 0, 0, 0);
  }
}

__global__ __launch_bounds__(256, 4) void mlp_kernel(
    const unsigned short* __restrict__ o_hf,
    const unsigned short* __restrict__ h0_hf, const unsigned short* __restrict__ h1_hf,
    const unsigned short* __restrict__ tooWt, const float* __restrict__ toob,
    const unsigned short* __restrict__ modW0t, const float* __restrict__ modb0,
    const unsigned short* __restrict__ modW1t, const float* __restrict__ modb1,
    const unsigned short* __restrict__ hvW0t, const float* __restrict__ hvb0,
    const float* __restrict__ outW0, const float* __restrict__ outb0,
    const float* __restrict__ outW1, const float* __restrict__ outb1,
    float* __restrict__ dout)
{
  __shared__ __align__(16) unsigned short buf0[32 * kPitch];  // o, then m0
  __shared__ __align__(16) unsigned short buf1[32 * kPitch];  // mod, then S
  __shared__ __align__(16) unsigned short hbuf[8 * kPitch];   // h0, then h1 (8 px)
  __shared__ __align__(16) float scratch[32 * 12];            // out partials

  int tid = threadIdx.x;
  int px0 = blockIdx.x * 8;          // 8 pixels x 4 batch = 32 rows
  int w = tid >> 6, ln = tid & 63;
  int c = ln & 15, q = ln >> 4;

  // ---- stage o (32 rows x 128) and h0 (8 px x 256) ----
#pragma unroll
  for (int i = 0; i < 2; i++) {
    int idx = i * 256 + tid;              // 512 x uint4 (8 fp16)
    int r = idx >> 4, c8 = (idx & 15) * 8;
    int b = r >> 3, px = r & 7;
    uint4 v = *(const uint4*)(o_hf + ((size_t)(b * kHW + px0 + px)) * 128 + c8);
    *(uint4*)&buf0[r * kPitch + c8] = v;
  }
  {
    int p = tid >> 5, c8 = (tid & 31) * 8;  // 256 x uint4 (8 px x 32)
    uint4 v = *(const uint4*)(h0_hf + ((size_t)(px0 + p)) * 256 + c8);
    *(uint4*)&hbuf[p * kPitch + c8] = v;
  }
  __syncthreads();

  f32x4 acc[8];
  const f32x4 zero4 = {0.f, 0.f, 0.f, 0.f};

  // ---- P1: mod = o @ tooW + toob -> buf1 ----
#pragma unroll
  for (int i = 0; i < 8; i++) acc[i] = zero4;
  gemm2m<128>(buf0, tooWt + (size_t)w * 64 * 128, acc, c, q);
  {
    float bias[4];
#pragma unroll
    for (int nt = 0; nt < 4; nt++) bias[nt] = toob[w * 64 + nt * 16 + c];
#pragma unroll
    for (int mt = 0; mt < 2; mt++)
#pragma unroll
      for (int nt = 0; nt < 4; nt++)
#pragma unroll
        for (int rg = 0; rg < 4; rg++) {
          int row = mt * 16 + q * 4 + rg, col = w * 64 + nt * 16 + c;
          buf1[row * kPitch + col] = f2h(acc[mt * 4 + nt][rg] + bias[nt]);
        }
  }
  __syncthreads();   // barrier A: mod ready; all o reads done

  // ---- P2: m0 = relu(h0 + mod @ modW0 + b) -> buf0 ----
#pragma unroll
  for (int i = 0; i < 8; i++) acc[i] = zero4;
  gemm2m<256>(buf1, modW0t + (size_t)w * 64 * 256, acc, c, q);
  {
    float bias[4], hr[4][4];
#pragma unroll
    for (int nt = 0; nt < 4; nt++) {
      int col = w * 64 + nt * 16 + c;
      bias[nt] = modb0[col];
#pragma unroll
      for (int rg = 0; rg < 4; rg++)
        hr[nt][rg] = h2f(hbuf[((q * 4 + rg) & 7) * kPitch + col]);
    }
#pragma unroll
    for (int mt = 0; mt < 2; mt++)
#pragma unroll
      for (int nt = 0; nt < 4; nt++)
#pragma unroll
        for (int rg = 0; rg < 4; rg++) {
          int row = mt * 16 + q * 4 + rg, col = w * 64 + nt * 16 + c;
          buf0[row * kPitch + col] =
              f2h(fmaxf(acc[mt * 4 + nt][rg] + bias[nt] + hr[nt][rg], 0.f));
        }
  }
  __syncthreads();   // barrier B: h0 consumed, m0 in buf0

  // ---- P3: stage h1; m1 = relu(h1 + mod @ modW1 + b); S = m0 + m1 -> buf1 ----
  {
    int p = tid >> 5, c8 = (tid & 31) * 8;
    uint4 v = *(const uint4*)(h1_hf + ((size_t)(px0 + p)) * 256 + c8);
    *(uint4*)&hbuf[p * kPitch + c8] = v;
  }
#pragma unroll
  for (int i = 0; i < 8; i++) acc[i] = zero4;
  gemm2m<256>(buf1, modW1t + (size_t)w * 64 * 256, acc, c, q);
  __syncthreads();   // barrier C: h1 staged AND all mod reads done
  {
    float bias[4], hr[4][4];
#pragma unroll
    for (int nt = 0; nt < 4; nt++) {
      int col = w * 64 + nt * 16 + c;
      bias[nt] = modb1[col];
#pragma unroll
      for (int rg = 0; rg < 4; rg++)
        hr[nt][rg] = h2f(hbuf[((q * 4 + rg) & 7) * kPitch + col]);
    }
#pragma unroll
    for (int mt = 0; mt < 2; mt++)
#pragma unroll
      for (int nt = 0; nt < 4; nt++)
#pragma unroll
        for (int rg = 0; rg < 4; rg++) {
          int row = mt * 16 + q * 4 + rg, col = w * 64 + nt * 16 + c;
          float m0v = h2f(buf0[row * kPitch + col]);
          float v = m0v + fmaxf(acc[mt * 4 + nt][rg] + bias[nt] + hr[nt][rg], 0.f);
          buf1[row * kPitch + col] = f2h(v);
        }
  }
  __syncthreads();   // barrier D: S ready

  // ---- P4: hv1 = relu(S @ hvW0 + b); fused out epilogue ----
#pragma unroll
  for (int i = 0; i < 8; i++) acc[i] = zero4;
  gemm2m<256>(buf1, hvW0t + (size_t)w * 64 * 256, acc, c, q);
  {
    float bias[4], w0v[4][3], w1v[4][3];
#pragma unroll
    for (int nt = 0; nt < 4; nt++) {
      int col = w * 64 + nt * 16 + c;
      bias[nt] = hvb0[col];
#pragma unroll
      for (int k = 0; k < 3; k++) {
        w0v[nt][k] = outW0[col * 3 + k];
        w1v[nt][k] = outW1[col * 3 + k];
      }
    }
#pragma unroll
    for (int mt = 0; mt < 2; mt++) {
      float pk[4][3];
#pragma unroll
      for (int rg = 0; rg < 4; rg++)
#pragma unroll
        for (int k = 0; k < 3; k++) pk[rg][k] = 0.f;
#pragma unroll
      for (int nt = 0; nt < 4; nt++) {
        int col = w * 64 + nt * 16 + c;
#pragma unroll
        for (int rg = 0; rg < 4; rg++) {
          int row = mt * 16 + q * 4 + rg;
          float hv1 = fmaxf(acc[mt * 4 + nt][rg] + bias[nt], 0.f);
          float m0v = h2f(buf0[row * kPitch + col]);
#pragma unroll
          for (int k = 0; k < 3; k++)
            pk[rg][k] += m0v * w0v[nt][k] + hv1 * w1v[nt][k];
        }
      }
#pragma unroll
      for (int s = 1; s < 16; s <<= 1)
#pragma unroll
        for (int rg = 0; rg < 4; rg++)
#pragma unroll
          for (int k = 0; k < 3; k++)
            pk[rg][k] += __shfl_xor(pk[rg][k], s, 64);
      if (c == 0) {
#pragma unroll
        for (int rg = 0; rg < 4; rg++) {
          int row = mt * 16 + q * 4 + rg;
#pragma unroll
          for (int k = 0; k < 3; k++)
            scratch[row * 12 + k * 4 + w] = pk[rg][k];
        }
      }
    }
  }
  __syncthreads();

  if (tid < 96) {
    int row = tid / 3, k = tid % 3;
    int b = row >> 3, px = px0 + (row & 7);
    float s = outb0[k] + outb1[k];
#pragma unroll
    for (int ww = 0; ww < 4; ww++) s += scratch[row * 12 + k * 4 + ww];
    dout[((size_t)b * kHW + px) * 3 + k] = s;
  }
}

// ---------------- launch ----------------
extern "C" void kernel_launch(void* const* d_in, const int* in_sizes, int n_in,
                              void* d_out, int out_size, void* d_ws, size_t ws_size,
                              hipStream_t stream) {
  const float* coords = (const float*)d_in[0];
  const float* tokens = (const float*)d_in[1];
  const float* Bq     = (const float*)d_in[2];
  const float* Bl0    = (const float*)d_in[3];
  const float* Bl1    = (const float*)d_in[4];
  const float* qW     = (const float*)d_in[5];
  const float* qb     = (const float*)d_in[6];
  const float* toqW   = (const float*)d_in[7];
  const float* tokvW  = (const float*)d_in[8];
  const float* tooW   = (const float*)d_in[9];
  const float* toob   = (const float*)d_in[10];
  const float* bwW0   = (const float*)d_in[11];
  const float* bwb0   = (const float*)d_in[12];
  const float* bwW1   = (const float*)d_in[13];
  const float* bwb1   = (const float*)d_in[14];
  const float* modW0  = (const float*)d_in[15];
  const float* modb0  = (const float*)d_in[16];
  const float* modW1  = (const float*)d_in[17];
  const float* modb1  = (const float*)d_in[18];
  const float* hvW0   = (const float*)d_in[19];
  const float* hvb0   = (const float*)d_in[20];
  const float* outW0  = (const float*)d_in[21];
  const float* outb0  = (const float*)d_in[22];
  const float* outW1  = (const float*)d_in[23];
  const float* outb1  = (const float*)d_in[24];

  char* ws = (char*)d_ws;
  unsigned short* h0_hf  = (unsigned short*)(ws + 0);         //    8 MB
  unsigned short* h1_hf  = (unsigned short*)(ws + 8388608);   //    8 MB
  unsigned short* o_hf   = (unsigned short*)(ws + 16777216);  //   16 MB
  unsigned short* kn_ws  = (unsigned short*)(ws + 33554432);  //  256 KB
  unsigned short* vt_ws  = (unsigned short*)(ws + 33816576);  //  256 KB
  unsigned short* tooWt  = (unsigned short*)(ws + 34078720);  //   64 KB
  unsigned short* modW0t = (unsigned short*)(ws + 34144256);  //  128 KB
  unsigned short* modW1t = (unsigned short*)(ws + 34275328);  //  128 KB
  unsigned short* hvW0t  = (unsigned short*)(ws + 34406400);  //  128 KB
  unsigned short* qWt    = (unsigned short*)(ws + 34537472);  //   32 KB
  unsigned short* bw0t   = (unsigned short*)(ws + 34570240);  //   32 KB
  unsigned short* bw1t   = (unsigned short*)(ws + 34603008);  //   32 KB
  unsigned short* toqWt  = (unsigned short*)(ws + 34635776);  //   64 KB

  prep_kernel<<<dim3(kB * kM + 64), 256, 0, stream>>>(
      tokens, tokvW, kn_ws, vt_ws,
      tooW, modW0, modW1, hvW0, qW, bwW0, bwW1, toqW,
      tooWt, modW0t, modW1t, hvW0t, qWt, bw0t, bw1t, toqWt);
  featattn_kernel<<<dim3(kHW / 32), 256, 0, stream>>>(
      coords, Bq, Bl0, Bl1, qb, bwb0, bwb1,
      qWt, bw0t, bw1t, toqWt,
      kn_ws, vt_ws,
      h0_hf, h1_hf, o_hf);
  mlp_kernel<<<dim3(kHW / 8), 256, 0, stream>>>(
      o_hf, h0_hf, h1_hf, tooWt, toob, modW0t, modb0, modW1t, modb1,
      hvW0t, hvb0, outW0, outb0, outW1, outb1, (float*)d_out);
}

// Round 9
// 246.519 us; speedup vs baseline: 1.1636x; 1.1636x over previous
//
#include <hip/hip_runtime.h>
#include <stdint.h>

constexpr int kHW = 16384;   // 128*128 pixels (grid shared across batch)
constexpr int kB  = 4;
constexpr int kM  = 256;     // tokens

typedef _Float16 half8 __attribute__((ext_vector_type(8)));  // 8 fp16 (4 VGPRs)
typedef __attribute__((ext_vector_type(4))) float f32x4;     // MFMA accum

// ---------------- helpers ----------------
__device__ __forceinline__ unsigned short f2h(float f) {
  _Float16 h = (_Float16)f;
  return __builtin_bit_cast(unsigned short, h);
}
__device__ __forceinline__ float h2f(unsigned short u) {
  return (float)__builtin_bit_cast(_Float16, u);
}

// ---------------- kernel 0: prep = wprep (64 blocks) + kv (1024 blocks), one launch ----------------
__global__ __launch_bounds__(256) void prep_kernel(
    const float* __restrict__ tokens, const float* __restrict__ tokvW,
    unsigned short* __restrict__ kn_ws, unsigned short* __restrict__ vt_ws,
    const float* __restrict__ tooW, const float* __restrict__ modW0,
    const float* __restrict__ modW1, const float* __restrict__ hvW0,
    const float* __restrict__ qW, const float* __restrict__ bwW0,
    const float* __restrict__ bwW1, const float* __restrict__ toqW,
    unsigned short* __restrict__ tooWt, unsigned short* __restrict__ modW0t,
    unsigned short* __restrict__ modW1t, unsigned short* __restrict__ hvW0t,
    unsigned short* __restrict__ qWt, unsigned short* __restrict__ bw0t,
    unsigned short* __restrict__ bw1t, unsigned short* __restrict__ toqWt)
{
  __shared__ __align__(16) float tok[256];
  int bx = blockIdx.x, tid = threadIdx.x;

  if (bx < kB * kM) {
    // ---- kv part ----
    int b = bx >> 8, j = bx & 255, c = tid;
    tok[c] = tokens[(b * kM + j) * 256 + c];
    __syncthreads();
    float acc = 0.f;
    for (int i4 = 0; i4 < 64; i4++) {
      float4 t4 = *(const float4*)&tok[i4 * 4];
      acc += t4.x * tokvW[(i4*4+0)*256 + c] + t4.y * tokvW[(i4*4+1)*256 + c]
           + t4.z * tokvW[(i4*4+2)*256 + c] + t4.w * tokvW[(i4*4+3)*256 + c];
    }
    unsigned short hv = f2h(acc);
    if (c < 128) {
      int h = c >> 6, dd = c & 63;
      kn_ws[((size_t)(b*2+h)*256 + j) * 64 + dd] = hv;
    } else {
      int c2 = c - 128;
      int h = c2 >> 6, dd = c2 & 63;
      vt_ws[((size_t)(b*2+h)*64 + dd) * 256 + j] = hv;
    }
  } else {
    // ---- wprep part: block t -> (matrix m, K-chunk ch of 8) ----
    int t = bx - kB * kM;          // 0..63
    int m = t >> 3, ch = t & 7;
    const float* Ws[8] = {tooW, modW0, modW1, hvW0, qW, bwW0, bwW1, toqW};
    unsigned short* Wts[8] = {tooWt, modW0t, modW1t, hvW0t, qWt, bw0t, bw1t, toqWt};
    const int Ks[8] = {128, 256, 256, 256, 64, 64, 64, 256};
    const int Ns[8] = {256, 256, 256, 256, 256, 256, 256, 128};
    const float* W = Ws[m];
    unsigned short* Wt = Wts[m];
    int K = Ks[m], N = Ns[m];
    int nkb = K / 8;               // 8, 16 or 32
    int per = nkb >> 3;            // 1, 2 or 4 iters per block
    int kb0 = ch * per;
    if (tid < N) {
      for (int kb = kb0; kb < kb0 + per; kb++) {
        unsigned short sv[8];
#pragma unroll
        for (int i = 0; i < 8; i++)
          sv[i] = f2h(W[(kb * 8 + i) * N + tid]);   // coalesced across tid
        *(uint4*)&Wt[tid * K + kb * 8] = *(const uint4*)sv;
      }
    }
  }
}

// ---------------- kernel 1: fused feat + attn, 32-px blocks (M=32, proven shapes) ----------------
constexpr int kAPitch = 264;   // xq / P_s pitch
constexpr int kQPitch = 136;   // qc pitch

__global__ __launch_bounds__(256, 2) void featattn_kernel(
    const float* __restrict__ coords,
    const float* __restrict__ Bq, const float* __restrict__ Bl0, const float* __restrict__ Bl1,
    const float* __restrict__ qb, const float* __restrict__ bwb0, const float* __restrict__ bwb1,
    const unsigned short* __restrict__ qWt, const unsigned short* __restrict__ bw0t,
    const unsigned short* __restrict__ bw1t, const unsigned short* __restrict__ toqWt,
    const unsigned short* __restrict__ kn_ws, const unsigned short* __restrict__ vt_ws,
    unsigned short* __restrict__ h0_hf, unsigned short* __restrict__ h1_hf,
    unsigned short* __restrict__ o_hf)
{
  __shared__ __align__(16) unsigned short arena[15360];
  __shared__ __align__(16) unsigned short qc_s[32 * kQPitch];
  __shared__ float t_s[32];
  __shared__ float coords_s[64];
  __shared__ float red_max[32][4];
  __shared__ float red_sum[32][4];

  unsigned short* ff  = arena;          // [3][32][72]
  unsigned short* xq  = arena + 6912;   // [32][264]
  unsigned short* P_s = arena;          // [32][264], after feat

  int tid = threadIdx.x;
  int px0 = blockIdx.x * 32;
  int w = tid >> 6, ln = tid & 63;
  int c = ln & 15, q = ln >> 4;

  const f32x4 zero4 = {0.f, 0.f, 0.f, 0.f};

  // ===== feat: Fourier features =====
  if (tid < 64) coords_s[tid] = coords[px0 * 2 + tid];
  __syncthreads();

#pragma unroll
  for (int r = 0; r < 24; r++) {
    int v = r * 256 + tid;
    int mat = v >> 11;
    int p = (v >> 6) & 31;
    int f = v & 63;
    int fr = f & 31;
    const float* Bm = (mat == 0) ? Bq : (mat == 1 ? Bl0 : Bl1);
    float x = coords_s[p * 2 + 0];
    float y = coords_s[p * 2 + 1];
    float proj = 6.283185307179586f * (x * Bm[fr*2+0] + y * Bm[fr*2+1]);
    float s, cc;
    __sincosf(proj, &s, &cc);
    ff[(mat * 32 + p) * 72 + f] = f2h((f < 32) ? cc : s);
  }
  if (tid < 32) {
    float x = coords_s[tid * 2 + 0];
    float y = coords_s[tid * 2 + 1];
    int row = min(max((int)(x * 16.0f), 0), 15);
    int col = min(max((int)(y * 16.0f), 0), 15);
    t_s[tid] = (float)(row * 16 + col) * (1.0f / 256.0f);
  }
  __syncthreads();

  // ===== feat: 3 GEMMs M=32, N=256, K=64 =====
  for (int mat = 0; mat < 3; mat++) {
    const unsigned short* Wt = (mat == 0) ? qWt : (mat == 1 ? bw0t : bw1t);
    const float* bias = (mat == 0) ? qb : (mat == 1 ? bwb0 : bwb1);
    f32x4 acc[8];
#pragma unroll
    for (int i = 0; i < 8; i++) acc[i] = zero4;
#pragma unroll
    for (int ks = 0; ks < 2; ks++) {
      int koff = ks * 32 + q * 8;
      half8 bfr[4];
#pragma unroll
      for (int nt = 0; nt < 4; nt++)
        bfr[nt] = *(const half8*)(Wt + (size_t)(w*64 + nt*16 + c) * 64 + koff);
      half8 afr[2];
#pragma unroll
      for (int mt = 0; mt < 2; mt++)
        afr[mt] = *(const half8*)(ff + (mat * 32 + mt*16 + c) * 72 + koff);
#pragma unroll
      for (int mt = 0; mt < 2; mt++)
#pragma unroll
        for (int nt = 0; nt < 4; nt++)
          acc[mt*4+nt] = __builtin_amdgcn_mfma_f32_16x16x32_f16(afr[mt], bfr[nt], acc[mt*4+nt], 0, 0, 0);
    }
    float bv[4];
#pragma unroll
    for (int nt = 0; nt < 4; nt++) bv[nt] = bias[w*64 + nt*16 + c];
#pragma unroll
    for (int mt = 0; mt < 2; mt++)
#pragma unroll
      for (int nt = 0; nt < 4; nt++)
#pragma unroll
        for (int rg = 0; rg < 4; rg++) {
          int row = mt*16 + q*4 + rg, col = w*64 + nt*16 + c;
          unsigned short hv = f2h(fmaxf(acc[mt*4+nt][rg] + bv[nt], 0.f));
          if (mat == 0)      xq[row * kAPitch + col] = hv;
          else if (mat == 1) h0_hf[((size_t)(px0 + row)) * 256 + col] = hv;
          else               h1_hf[((size_t)(px0 + row)) * 256 + col] = hv;
        }
  }
  __syncthreads();   // xq ready

  // ===== feat: q GEMM M=32, N=128, K=256 -> qc_s =====
  {
    f32x4 acc2[4];
#pragma unroll
    for (int i = 0; i < 4; i++) acc2[i] = zero4;
#pragma unroll
    for (int kt = 0; kt < 8; kt++) {
      int koff = kt * 32 + q * 8;
      half8 bfr[2];
#pragma unroll
      for (int nt = 0; nt < 2; nt++)
        bfr[nt] = *(const half8*)(toqWt + (size_t)(w*32 + nt*16 + c) * 256 + koff);
      half8 afr[2];
#pragma unroll
      for (int mt = 0; mt < 2; mt++)
        afr[mt] = *(const half8*)(xq + (mt*16 + c) * kAPitch + koff);
#pragma unroll
      for (int mt = 0; mt < 2; mt++)
#pragma unroll
        for (int nt = 0; nt < 2; nt++)
          acc2[mt*2+nt] = __builtin_amdgcn_mfma_f32_16x16x32_f16(afr[mt], bfr[nt], acc2[mt*2+nt], 0, 0, 0);
    }
#pragma unroll
    for (int mt = 0; mt < 2; mt++)
#pragma unroll
      for (int nt = 0; nt < 2; nt++)
#pragma unroll
        for (int rg = 0; rg < 4; rg++) {
          int row = mt*16 + q*4 + rg, col = w*32 + nt*16 + c;
          qc_s[row * kQPitch + col] = f2h(acc2[mt*2+nt][rg]);
        }
  }

  // ===== attn: loop over batch & head; qc stays in LDS =====
  for (int b = 0; b < kB; b++) {
    for (int h = 0; h < 2; h++) {
      __syncthreads();   // qc visible; previous P_s reads done

      // QK^T: M=32, N=256 (wave strip of 64), K=64
      f32x4 acc[8];
#pragma unroll
      for (int i = 0; i < 8; i++) acc[i] = zero4;
      const unsigned short* kbase = kn_ws + (size_t)(b*2+h) * 256 * 64;
#pragma unroll
      for (int ks = 0; ks < 2; ks++) {
        int koff = ks * 32 + q * 8;
        half8 a0 = *(const half8*)(qc_s + c * kQPitch + h*64 + koff);
        half8 a1 = *(const half8*)(qc_s + (16 + c) * kQPitch + h*64 + koff);
#pragma unroll
        for (int nt = 0; nt < 4; nt++) {
          half8 bf = *(const half8*)(kbase + (size_t)(w*64 + nt*16 + c) * 64 + koff);
          acc[0*4+nt] = __builtin_amdgcn_mfma_f32_16x16x32_f16(a0, bf, acc[0*4+nt], 0, 0, 0);
          acc[1*4+nt] = __builtin_amdgcn_mfma_f32_16x16x32_f16(a1, bf, acc[1*4+nt], 0, 0, 0);
        }
      }

      // bias + scale, row max
      float lm[2][4];
#pragma unroll
      for (int mt = 0; mt < 2; mt++)
#pragma unroll
        for (int rg = 0; rg < 4; rg++) {
          int row = mt*16 + q*4 + rg;
          float tv = t_s[row];
          float mx = -1e30f;
#pragma unroll
          for (int nt = 0; nt < 4; nt++) {
            int token = w*64 + nt*16 + c;
            float pos = ((float)token + 0.5f) * (1.0f / 256.0f);
            float db = tv - pos;
            float sb = acc[mt*4+nt][rg] * 0.125f - 10.0f * db * db;
            acc[mt*4+nt][rg] = sb;
            mx = fmaxf(mx, sb);
          }
          lm[mt][rg] = mx;
        }
#pragma unroll
      for (int s = 1; s < 16; s <<= 1)
#pragma unroll
        for (int mt = 0; mt < 2; mt++)
#pragma unroll
          for (int rg = 0; rg < 4; rg++)
            lm[mt][rg] = fmaxf(lm[mt][rg], __shfl_xor(lm[mt][rg], s, 64));
      if (c == 0) {
#pragma unroll
        for (int mt = 0; mt < 2; mt++)
#pragma unroll
          for (int rg = 0; rg < 4; rg++)
            red_max[mt*16 + q*4 + rg][w] = lm[mt][rg];
      }
      __syncthreads();

      // exp -> P_s, partial sums
      float ps[2][4];
#pragma unroll
      for (int mt = 0; mt < 2; mt++)
#pragma unroll
        for (int rg = 0; rg < 4; rg++) {
          int row = mt*16 + q*4 + rg;
          float gm = fmaxf(fmaxf(red_max[row][0], red_max[row][1]),
                           fmaxf(red_max[row][2], red_max[row][3]));
          float sum = 0.f;
#pragma unroll
          for (int nt = 0; nt < 4; nt++) {
            float e = __expf(acc[mt*4+nt][rg] - gm);
            sum += e;
            P_s[row * kAPitch + w*64 + nt*16 + c] = f2h(e);
          }
          ps[mt][rg] = sum;
        }
#pragma unroll
      for (int s = 1; s < 16; s <<= 1)
#pragma unroll
        for (int mt = 0; mt < 2; mt++)
#pragma unroll
          for (int rg = 0; rg < 4; rg++)
            ps[mt][rg] += __shfl_xor(ps[mt][rg], s, 64);
      if (c == 0) {
#pragma unroll
        for (int mt = 0; mt < 2; mt++)
#pragma unroll
          for (int rg = 0; rg < 4; rg++)
            red_sum[mt*16 + q*4 + rg][w] = ps[mt][rg];
      }
      __syncthreads();

      // PV: wave w -> dh cols [w*16, w*16+16), K=256
      f32x4 oacc[2] = {zero4, zero4};
      const unsigned short* vbase = vt_ws + (size_t)(b*2+h) * 64 * 256;
#pragma unroll
      for (int kt = 0; kt < 8; kt++) {
        int koff = kt * 32 + q * 8;
        half8 bf = *(const half8*)(vbase + (size_t)(w*16 + c) * 256 + koff);
        half8 a0 = *(const half8*)(P_s + (0*16 + c) * kAPitch + koff);
        half8 a1 = *(const half8*)(P_s + (1*16 + c) * kAPitch + koff);
        oacc[0] = __builtin_amdgcn_mfma_f32_16x16x32_f16(a0, bf, oacc[0], 0, 0, 0);
        oacc[1] = __builtin_amdgcn_mfma_f32_16x16x32_f16(a1, bf, oacc[1], 0, 0, 0);
      }
#pragma unroll
      for (int mt = 0; mt < 2; mt++)
#pragma unroll
        for (int rg = 0; rg < 4; rg++) {
          int row = mt*16 + q*4 + rg;
          float rinv = 1.0f / (red_sum[row][0] + red_sum[row][1] +
                               red_sum[row][2] + red_sum[row][3]);
          o_hf[((size_t)(b * kHW + px0 + row)) * 128 + h*64 + w*16 + c] =
              f2h(oacc[mt][rg] * rinv);
        }
    }
  }
}

// ---------------- kernel 2: MFMA MLP chain, fp16, M=64 rows (16 px x 4 batch) ----------------
// R0/R6 exact structure: the no-spill minimum-phase-chain configuration (76 us).
constexpr int kPitch = 264;   // fp16 LDS pitch

template <int KD>
__device__ __forceinline__ void gemm4(
    const unsigned short* abuf, const unsigned short* wt,
    f32x4* acc /*[4*4]*/, int c, int q)
{
#pragma unroll
  for (int ks = 0; ks < KD / 32; ks++) {
    int koff = ks * 32 + q * 8;
    half8 bfr[4];
#pragma unroll
    for (int nt = 0; nt < 4; nt++)
      bfr[nt] = *(const half8*)(wt + (nt * 16 + c) * KD + koff);
    half8 afr[4];
#pragma unroll
    for (int mt = 0; mt < 4; mt++)
      afr[mt] = *(const half8*)(abuf + (mt * 16 + c) * kPitch + koff);
#pragma unroll
    for (int mt = 0; mt < 4; mt++)
#pragma unroll
      for (int nt = 0; nt < 4; nt++)
        acc[mt * 4 + nt] = __builtin_amdgcn_mfma_f32_16x16x32_f16(afr[mt], bfr[nt], acc[mt * 4 + nt], 0, 0, 0);
  }
}

__global__ __launch_bounds__(256, 2) void mlp_kernel(
    const unsigned short* __restrict__ o_hf,
    const unsigned short* __restrict__ h0_hf, const unsigned short* __restrict__ h1_hf,
    const unsigned short* __restrict__ tooWt, const float* __restrict__ toob,
    const unsigned short* __restrict__ modW0t, const float* __restrict__ modb0,
    const unsigned short* __restrict__ modW1t, const float* __restrict__ modb1,
    const unsigned short* __restrict__ hvW0t, const float* __restrict__ hvb0,
    const float* __restrict__ outW0, const float* __restrict__ outb0,
    const float* __restrict__ outW1, const float* __restrict__ outb1,
    float* __restrict__ dout)
{
  __shared__ __align__(16) unsigned short buf0[64 * kPitch];  // o, then m0 (hv0)
  __shared__ __align__(16) unsigned short buf1[64 * kPitch];  // mod, then S
  __shared__ __align__(16) unsigned short hbuf[16 * kPitch];  // h0, then h1 (per-pixel)
  __shared__ __align__(16) float scratch[64 * 3 * 4];         // out partials [row][k][wave]

  int tid = threadIdx.x;
  int px0 = blockIdx.x * 16;
  int w = tid >> 6, ln = tid & 63;
  int c = ln & 15, q = ln >> 4;

  // ---- stage o (64 rows x 128) and h0 (16 px x 256) ----
#pragma unroll
  for (int i = 0; i < 4; i++) {
    int idx = i * 256 + tid;              // 1024 x uint4 (8 fp16)
    int r = idx >> 4, c8 = (idx & 15) * 8;
    int b = r >> 4, px = r & 15;
    uint4 v = *(const uint4*)(o_hf + ((size_t)(b * kHW + px0 + px)) * 128 + c8);
    *(uint4*)&buf0[r * kPitch + c8] = v;
  }
#pragma unroll
  for (int i = 0; i < 2; i++) {
    int idx = i * 256 + tid;              // 512 x uint4
    int p = idx >> 5, c8 = (idx & 31) * 8;
    uint4 v = *(const uint4*)(h0_hf + ((size_t)(px0 + p)) * 256 + c8);
    *(uint4*)&hbuf[p * kPitch + c8] = v;
  }
  __syncthreads();

  f32x4 acc[16];
  const f32x4 zero4 = {0.f, 0.f, 0.f, 0.f};

  // ---- P1: mod = o @ tooW + toob -> buf1 ----
#pragma unroll
  for (int i = 0; i < 16; i++) acc[i] = zero4;
  gemm4<128>(buf0, tooWt + (size_t)w * 64 * 128, acc, c, q);
  {
    float bias[4];
#pragma unroll
    for (int nt = 0; nt < 4; nt++) bias[nt] = toob[w * 64 + nt * 16 + c];
#pragma unroll
    for (int mt = 0; mt < 4; mt++)
#pragma unroll
      for (int nt = 0; nt < 4; nt++)
#pragma unroll
        for (int rg = 0; rg < 4; rg++) {
          int row = mt * 16 + q * 4 + rg, col = w * 64 + nt * 16 + c;
          buf1[row * kPitch + col] = f2h(acc[mt * 4 + nt][rg] + bias[nt]);
        }
  }
  __syncthreads();   // barrier A: mod ready; all o reads done

  // ---- P2: m0 = relu(h0 + mod @ modW0 + b) -> buf0 ----
#pragma unroll
  for (int i = 0; i < 16; i++) acc[i] = zero4;
  gemm4<256>(buf1, modW0t + (size_t)w * 64 * 256, acc, c, q);
  {
    float bias[4], hr[4][4];
#pragma unroll
    for (int nt = 0; nt < 4; nt++) {
      int col = w * 64 + nt * 16 + c;
      bias[nt] = modb0[col];
#pragma unroll
      for (int rg = 0; rg < 4; rg++)
        hr[nt][rg] = h2f(hbuf[(q * 4 + rg) * kPitch + col]);
    }
#pragma unroll
    for (int mt = 0; mt < 4; mt++)
#pragma unroll
      for (int nt = 0; nt < 4; nt++)
#pragma unroll
        for (int rg = 0; rg < 4; rg++) {
          int row = mt * 16 + q * 4 + rg, col = w * 64 + nt * 16 + c;
          buf0[row * kPitch + col] =
              f2h(fmaxf(acc[mt * 4 + nt][rg] + bias[nt] + hr[nt][rg], 0.f));
        }
  }
  __syncthreads();   // barrier B: h0 consumed, m0 in buf0

  // ---- P3: stage h1; m1 = relu(h1 + mod @ modW1 + b); S = m0 + m1 -> buf1 ----
#pragma unroll
  for (int i = 0; i < 2; i++) {
    int idx = i * 256 + tid;
    int p = idx >> 5, c8 = (idx & 31) * 8;
    uint4 v = *(const uint4*)(h1_hf + ((size_t)(px0 + p)) * 256 + c8);
    *(uint4*)&hbuf[p * kPitch + c8] = v;
  }
#pragma unroll
  for (int i = 0; i < 16; i++) acc[i] = zero4;
  gemm4<256>(buf1, modW1t + (size_t)w * 64 * 256, acc, c, q);
  __syncthreads();   // barrier C: h1 staged AND all mod reads done
  {
    float bias[4], hr[4][4];
#pragma unroll
    for (int nt = 0; nt < 4; nt++) {
      int col = w * 64 + nt * 16 + c;
      bias[nt] = modb1[col];
#pragma unroll
      for (int rg = 0; rg < 4; rg++)
        hr[nt][rg] = h2f(hbuf[(q * 4 + rg) * kPitch + col]);
    }
#pragma unroll
    for (int mt = 0; mt < 4; mt++)
#pragma unroll
      for (int nt = 0; nt < 4; nt++)
#pragma unroll
        for (int rg = 0; rg < 4; rg++) {
          int row = mt * 16 + q * 4 + rg, col = w * 64 + nt * 16 + c;
          float m0v = h2f(buf0[row * kPitch + col]);
          float v = m0v + fmaxf(acc[mt * 4 + nt][rg] + bias[nt] + hr[nt][rg], 0.f);
          buf1[row * kPitch + col] = f2h(v);
        }
  }
  __syncthreads();   // barrier D: S ready

  // ---- P4: hv1 = relu(S @ hvW0 + b); fused out epilogue ----
#pragma unroll
  for (int i = 0; i < 16; i++) acc[i] = zero4;
  gemm4<256>(buf1, hvW0t + (size_t)w * 64 * 256, acc, c, q);
  {
    float bias[4], w0v[4][3], w1v[4][3];
#pragma unroll
    for (int nt = 0; nt < 4; nt++) {
      int col = w * 64 + nt * 16 + c;
      bias[nt] = hvb0[col];
#pragma unroll
      for (int k = 0; k < 3; k++) {
        w0v[nt][k] = outW0[col * 3 + k];
        w1v[nt][k] = outW1[col * 3 + k];
      }
    }
#pragma unroll
    for (int mt = 0; mt < 4; mt++) {
      float pk[4][3];
#pragma unroll
      for (int rg = 0; rg < 4; rg++)
#pragma unroll
        for (int k = 0; k < 3; k++) pk[rg][k] = 0.f;
#pragma unroll
      for (int nt = 0; nt < 4; nt++) {
        int col = w * 64 + nt * 16 + c;
#pragma unroll
        for (int rg = 0; rg < 4; rg++) {
          int row = mt * 16 + q * 4 + rg;
          float hv1 = fmaxf(acc[mt * 4 + nt][rg] + bias[nt], 0.f);
          float m0v = h2f(buf0[row * kPitch + col]);
#pragma unroll
          for (int k = 0; k < 3; k++)
            pk[rg][k] += m0v * w0v[nt][k] + hv1 * w1v[nt][k];
        }
      }
#pragma unroll
      for (int s = 1; s < 16; s <<= 1)
#pragma unroll
        for (int rg = 0; rg < 4; rg++)
#pragma unroll
          for (int k = 0; k < 3; k++)
            pk[rg][k] += __shfl_xor(pk[rg][k], s, 64);
      if (c == 0) {
#pragma unroll
        for (int rg = 0; rg < 4; rg++) {
          int row = mt * 16 + q * 4 + rg;
#pragma unroll
          for (int k = 0; k < 3; k++)
            scratch[row * 12 + k * 4 + w] = pk[rg][k];
        }
      }
    }
  }
  __syncthreads();

  if (tid < 192) {
    int row = tid / 3, k = tid % 3;
    int b = row >> 4, px = px0 + (row & 15);
    float s = outb0[k] + outb1[k];
#pragma unroll
    for (int ww = 0; ww < 4; ww++) s += scratch[row * 12 + k * 4 + ww];
    dout[((size_t)b * kHW + px) * 3 + k] = s;
  }
}

// ---------------- launch ----------------
extern "C" void kernel_launch(void* const* d_in, const int* in_sizes, int n_in,
                              void* d_out, int out_size, void* d_ws, size_t ws_size,
                              hipStream_t stream) {
  const float* coords = (const float*)d_in[0];
  const float* tokens = (const float*)d_in[1];
  const float* Bq     = (const float*)d_in[2];
  const float* Bl0    = (const float*)d_in[3];
  const float* Bl1    = (const float*)d_in[4];
  const float* qW     = (const float*)d_in[5];
  const float* qb     = (const float*)d_in[6];
  const float* toqW   = (const float*)d_in[7];
  const float* tokvW  = (const float*)d_in[8];
  const float* tooW   = (const float*)d_in[9];
  const float* toob   = (const float*)d_in[10];
  const float* bwW0   = (const float*)d_in[11];
  const float* bwb0   = (const float*)d_in[12];
  const float* bwW1   = (const float*)d_in[13];
  const float* bwb1   = (const float*)d_in[14];
  const float* modW0  = (const float*)d_in[15];
  const float* modb0  = (const float*)d_in[16];
  const float* modW1  = (const float*)d_in[17];
  const float* modb1  = (const float*)d_in[18];
  const float* hvW0   = (const float*)d_in[19];
  const float* hvb0   = (const float*)d_in[20];
  const float* outW0  = (const float*)d_in[21];
  const float* outb0  = (const float*)d_in[22];
  const float* outW1  = (const float*)d_in[23];
  const float* outb1  = (const float*)d_in[24];

  char* ws = (char*)d_ws;
  unsigned short* h0_hf  = (unsigned short*)(ws + 0);         //    8 MB
  unsigned short* h1_hf  = (unsigned short*)(ws + 8388608);   //    8 MB
  unsigned short* o_hf   = (unsigned short*)(ws + 16777216);  //   16 MB
  unsigned short* kn_ws  = (unsigned short*)(ws + 33554432);  //  256 KB
  unsigned short* vt_ws  = (unsigned short*)(ws + 33816576);  //  256 KB
  unsigned short* tooWt  = (unsigned short*)(ws + 34078720);  //   64 KB
  unsigned short* modW0t = (unsigned short*)(ws + 34144256);  //  128 KB
  unsigned short* modW1t = (unsigned short*)(ws + 34275328);  //  128 KB
  unsigned short* hvW0t  = (unsigned short*)(ws + 34406400);  //  128 KB
  unsigned short* qWt    = (unsigned short*)(ws + 34537472);  //   32 KB
  unsigned short* bw0t   = (unsigned short*)(ws + 34570240);  //   32 KB
  unsigned short* bw1t   = (unsigned short*)(ws + 34603008);  //   32 KB
  unsigned short* toqWt  = (unsigned short*)(ws + 34635776);  //   64 KB

  prep_kernel<<<dim3(kB * kM + 64), 256, 0, stream>>>(
      tokens, tokvW, kn_ws, vt_ws,
      tooW, modW0, modW1, hvW0, qW, bwW0, bwW1, toqW,
      tooWt, modW0t, modW1t, hvW0t, qWt, bw0t, bw1t, toqWt);
  featattn_kernel<<<dim3(kHW / 32), 256, 0, stream>>>(
      coords, Bq, Bl0, Bl1, qb, bwb0, bwb1,
      qWt, bw0t, bw1t, toqWt,
      kn_ws, vt_ws,
      h0_hf, h1_hf, o_hf);
  mlp_kernel<<<dim3(kHW / 16), 256, 0, stream>>>(
      o_hf, h0_hf, h1_hf, tooWt, toob, modW0t, modb0, modW1t, modb1,
      hvW0t, hvb0, outW0, outb0, outW1, outb1, (float*)d_out);
}

// Round 10
// 240.719 us; speedup vs baseline: 1.1916x; 1.0241x over previous
//
#include <hip/hip_runtime.h>
#include <stdint.h>

constexpr int kHW = 16384;   // 128*128 pixels (grid shared across batch)
constexpr int kB  = 4;
constexpr int kM  = 256;     // tokens

typedef _Float16 half8 __attribute__((ext_vector_type(8)));  // 8 fp16 (4 VGPRs)
typedef __attribute__((ext_vector_type(4))) float f32x4;     // MFMA accum

// ---------------- helpers ----------------
__device__ __forceinline__ unsigned short f2h(float f) {
  _Float16 h = (_Float16)f;
  return __builtin_bit_cast(unsigned short, h);
}
__device__ __forceinline__ float h2f(unsigned short u) {
  return (float)__builtin_bit_cast(_Float16, u);
}

// ---------------- kernel 0: prep = wprep (64 blocks) + kv (1024 blocks), one launch ----------------
__global__ __launch_bounds__(256) void prep_kernel(
    const float* __restrict__ tokens, const float* __restrict__ tokvW,
    unsigned short* __restrict__ kn_ws, unsigned short* __restrict__ vt_ws,
    const float* __restrict__ tooW, const float* __restrict__ modW0,
    const float* __restrict__ modW1, const float* __restrict__ hvW0,
    const float* __restrict__ qW, const float* __restrict__ bwW0,
    const float* __restrict__ bwW1, const float* __restrict__ toqW,
    unsigned short* __restrict__ tooWt, unsigned short* __restrict__ modW0t,
    unsigned short* __restrict__ modW1t, unsigned short* __restrict__ hvW0t,
    unsigned short* __restrict__ qWt, unsigned short* __restrict__ bw0t,
    unsigned short* __restrict__ bw1t, unsigned short* __restrict__ toqWt)
{
  __shared__ __align__(16) float tok[256];
  int bx = blockIdx.x, tid = threadIdx.x;

  if (bx < kB * kM) {
    // ---- kv part ----
    int b = bx >> 8, j = bx & 255, c = tid;
    tok[c] = tokens[(b * kM + j) * 256 + c];
    __syncthreads();
    float acc = 0.f;
    for (int i4 = 0; i4 < 64; i4++) {
      float4 t4 = *(const float4*)&tok[i4 * 4];
      acc += t4.x * tokvW[(i4*4+0)*256 + c] + t4.y * tokvW[(i4*4+1)*256 + c]
           + t4.z * tokvW[(i4*4+2)*256 + c] + t4.w * tokvW[(i4*4+3)*256 + c];
    }
    unsigned short hv = f2h(acc);
    if (c < 128) {
      int h = c >> 6, dd = c & 63;
      kn_ws[((size_t)(b*2+h)*256 + j) * 64 + dd] = hv;
    } else {
      int c2 = c - 128;
      int h = c2 >> 6, dd = c2 & 63;
      vt_ws[((size_t)(b*2+h)*64 + dd) * 256 + j] = hv;
    }
  } else {
    // ---- wprep part: block t -> (matrix m, K-chunk ch of 8) ----
    int t = bx - kB * kM;          // 0..63
    int m = t >> 3, ch = t & 7;
    const float* Ws[8] = {tooW, modW0, modW1, hvW0, qW, bwW0, bwW1, toqW};
    unsigned short* Wts[8] = {tooWt, modW0t, modW1t, hvW0t, qWt, bw0t, bw1t, toqWt};
    const int Ks[8] = {128, 256, 256, 256, 64, 64, 64, 256};
    const int Ns[8] = {256, 256, 256, 256, 256, 256, 256, 128};
    const float* W = Ws[m];
    unsigned short* Wt = Wts[m];
    int K = Ks[m], N = Ns[m];
    int nkb = K / 8;               // 8, 16 or 32
    int per = nkb >> 3;            // 1, 2 or 4 iters per block
    int kb0 = ch * per;
    if (tid < N) {
      for (int kb = kb0; kb < kb0 + per; kb++) {
        unsigned short sv[8];
#pragma unroll
        for (int i = 0; i < 8; i++)
          sv[i] = f2h(W[(kb * 8 + i) * N + tid]);   // coalesced across tid
        *(uint4*)&Wt[tid * K + kb * 8] = *(const uint4*)sv;
      }
    }
  }
}

// ---------------- kernel 2: MFMA per-pixel features (shared across batch) ----------------
constexpr int kFPitch = 72;    // fp16 pitch for ff rows (144 B = 9*16)
constexpr int kXPitch = 264;   // fp16 pitch for xq rows

__global__ __launch_bounds__(256, 2) void feat_kernel(
    const float* __restrict__ coords,
    const float* __restrict__ Bq, const float* __restrict__ Bl0, const float* __restrict__ Bl1,
    const float* __restrict__ qb, const float* __restrict__ bwb0, const float* __restrict__ bwb1,
    const unsigned short* __restrict__ qWt, const unsigned short* __restrict__ bw0t,
    const unsigned short* __restrict__ bw1t, const unsigned short* __restrict__ toqWt,
    float* __restrict__ t_ws, unsigned short* __restrict__ qc_ws,
    unsigned short* __restrict__ h0_hf, unsigned short* __restrict__ h1_hf)
{
  __shared__ __align__(16) unsigned short ff_s[3][32][kFPitch];
  __shared__ __align__(16) unsigned short xq_s[32][kXPitch];
  __shared__ float coords_s[64];

  int tid = threadIdx.x;
  int px0 = blockIdx.x * 32;
  int w = tid >> 6, ln = tid & 63;
  int c = ln & 15, q = ln >> 4;

  if (tid < 64) coords_s[tid] = coords[px0 * 2 + tid];
  __syncthreads();

  // ---- Fourier features: 3 mats * 32 px * 64 f = 6144 vals, 24/thread ----
#pragma unroll
  for (int r = 0; r < 24; r++) {
    int v = r * 256 + tid;
    int mat = v >> 11;
    int p = (v >> 6) & 31;
    int f = v & 63;
    int fr = f & 31;
    const float* Bm = (mat == 0) ? Bq : (mat == 1 ? Bl0 : Bl1);
    float x = coords_s[p * 2 + 0];
    float y = coords_s[p * 2 + 1];
    float proj = 6.283185307179586f * (x * Bm[fr*2+0] + y * Bm[fr*2+1]);
    float s, cc;
    __sincosf(proj, &s, &cc);
    ff_s[mat][p][f] = f2h((f < 32) ? cc : s);
  }
  if (tid < 32) {
    float x = coords_s[tid * 2 + 0];
    float y = coords_s[tid * 2 + 1];
    int row = min(max((int)(x * 16.0f), 0), 15);
    int col = min(max((int)(y * 16.0f), 0), 15);
    t_ws[px0 + tid] = (float)(row * 16 + col) * (1.0f / 256.0f);
  }
  __syncthreads();

  const f32x4 zero4 = {0.f, 0.f, 0.f, 0.f};

  // ---- 3 GEMMs: M=32, N=256 (wave owns 64 cols), K=64 ----
  for (int mat = 0; mat < 3; mat++) {
    const unsigned short* Wt = (mat == 0) ? qWt : (mat == 1 ? bw0t : bw1t);
    const float* bias = (mat == 0) ? qb : (mat == 1 ? bwb0 : bwb1);
    f32x4 acc[8];
#pragma unroll
    for (int i = 0; i < 8; i++) acc[i] = zero4;
#pragma unroll
    for (int ks = 0; ks < 2; ks++) {
      int koff = ks * 32 + q * 8;
      half8 bfr[4];
#pragma unroll
      for (int nt = 0; nt < 4; nt++)
        bfr[nt] = *(const half8*)(Wt + (size_t)(w*64 + nt*16 + c) * 64 + koff);
      half8 afr[2];
#pragma unroll
      for (int mt = 0; mt < 2; mt++)
        afr[mt] = *(const half8*)(&ff_s[mat][mt*16 + c][koff]);
#pragma unroll
      for (int mt = 0; mt < 2; mt++)
#pragma unroll
        for (int nt = 0; nt < 4; nt++)
          acc[mt*4+nt] = __builtin_amdgcn_mfma_f32_16x16x32_f16(afr[mt], bfr[nt], acc[mt*4+nt], 0, 0, 0);
    }
    float bv[4];
#pragma unroll
    for (int nt = 0; nt < 4; nt++) bv[nt] = bias[w*64 + nt*16 + c];
#pragma unroll
    for (int mt = 0; mt < 2; mt++)
#pragma unroll
      for (int nt = 0; nt < 4; nt++)
#pragma unroll
        for (int rg = 0; rg < 4; rg++) {
          int row = mt*16 + q*4 + rg, col = w*64 + nt*16 + c;
          unsigned short hv = f2h(fmaxf(acc[mt*4+nt][rg] + bv[nt], 0.f));
          if (mat == 0)      xq_s[row][col] = hv;
          else if (mat == 1) h0_hf[((size_t)(px0 + row)) * 256 + col] = hv;
          else               h1_hf[((size_t)(px0 + row)) * 256 + col] = hv;
        }
  }
  __syncthreads();   // xq_s ready

  // ---- q GEMM: M=32, N=128 (wave owns 32 cols), K=256, no bias ----
  {
    f32x4 acc2[4];
#pragma unroll
    for (int i = 0; i < 4; i++) acc2[i] = zero4;
#pragma unroll
    for (int kt = 0; kt < 8; kt++) {
      int koff = kt * 32 + q * 8;
      half8 bfr[2];
#pragma unroll
      for (int nt = 0; nt < 2; nt++)
        bfr[nt] = *(const half8*)(toqWt + (size_t)(w*32 + nt*16 + c) * 256 + koff);
      half8 afr[2];
#pragma unroll
      for (int mt = 0; mt < 2; mt++)
        afr[mt] = *(const half8*)(&xq_s[mt*16 + c][koff]);
#pragma unroll
      for (int mt = 0; mt < 2; mt++)
#pragma unroll
        for (int nt = 0; nt < 2; nt++)
          acc2[mt*2+nt] = __builtin_amdgcn_mfma_f32_16x16x32_f16(afr[mt], bfr[nt], acc2[mt*2+nt], 0, 0, 0);
    }
#pragma unroll
    for (int mt = 0; mt < 2; mt++)
#pragma unroll
      for (int nt = 0; nt < 2; nt++)
#pragma unroll
        for (int rg = 0; rg < 4; rg++) {
          int row = mt*16 + q*4 + rg, col = w*32 + nt*16 + c;
          qc_ws[((size_t)(px0 + row)) * 128 + col] = f2h(acc2[mt*2+nt][rg]);
        }
  }
}

// ---------------- kernel 3: MFMA cross attention with spatial bias (fp16) ----------------
constexpr int kPPitch = 264;

__global__ __launch_bounds__(256, 2) void attn_kernel(
    const unsigned short* __restrict__ kn_ws,
    const unsigned short* __restrict__ vt_ws,
    const unsigned short* __restrict__ qc_ws,
    const float* __restrict__ t_ws,
    unsigned short* __restrict__ o_hf)
{
  __shared__ __align__(16) unsigned short P_s[32 * kPPitch];
  __shared__ float t_s[32];
  __shared__ float red_max[32][4];
  __shared__ float red_sum[32][4];

  int b = blockIdx.y;
  int px0 = blockIdx.x * 32;
  int tid = threadIdx.x;
  int w = tid >> 6, ln = tid & 63;
  int c = ln & 15, q = ln >> 4;

  if (tid < 32) t_s[tid] = t_ws[px0 + tid];

  const f32x4 zero4 = {0.f, 0.f, 0.f, 0.f};

  for (int h = 0; h < 2; h++) {
    __syncthreads();

    // ---- QK^T: M=32, N=256 (wave strip of 64), K=64 ----
    f32x4 acc[8];
#pragma unroll
    for (int i = 0; i < 8; i++) acc[i] = zero4;
    const unsigned short* kbase = kn_ws + (size_t)(b*2+h) * 256 * 64;
#pragma unroll
    for (int ks = 0; ks < 2; ks++) {
      int koff = ks * 32 + q * 8;
      half8 a0 = *(const half8*)(qc_ws + (size_t)(px0 + c) * 128 + h*64 + koff);
      half8 a1 = *(const half8*)(qc_ws + (size_t)(px0 + 16 + c) * 128 + h*64 + koff);
#pragma unroll
      for (int nt = 0; nt < 4; nt++) {
        half8 bf = *(const half8*)(kbase + (size_t)(w*64 + nt*16 + c) * 64 + koff);
        acc[0*4+nt] = __builtin_amdgcn_mfma_f32_16x16x32_f16(a0, bf, acc[0*4+nt], 0, 0, 0);
        acc[1*4+nt] = __builtin_amdgcn_mfma_f32_16x16x32_f16(a1, bf, acc[1*4+nt], 0, 0, 0);
      }
    }

    // ---- bias + scale, per-lane row max ----
    float lm[2][4];
#pragma unroll
    for (int mt = 0; mt < 2; mt++)
#pragma unroll
      for (int rg = 0; rg < 4; rg++) {
        int row = mt*16 + q*4 + rg;
        float tv = t_s[row];
        float mx = -1e30f;
#pragma unroll
        for (int nt = 0; nt < 4; nt++) {
          int token = w*64 + nt*16 + c;
          float pos = ((float)token + 0.5f) * (1.0f / 256.0f);
          float db = tv - pos;
          float sb = acc[mt*4+nt][rg] * 0.125f - 10.0f * db * db;
          acc[mt*4+nt][rg] = sb;
          mx = fmaxf(mx, sb);
        }
        lm[mt][rg] = mx;
      }
#pragma unroll
    for (int s = 1; s < 16; s <<= 1)
#pragma unroll
      for (int mt = 0; mt < 2; mt++)
#pragma unroll
        for (int rg = 0; rg < 4; rg++)
          lm[mt][rg] = fmaxf(lm[mt][rg], __shfl_xor(lm[mt][rg], s, 64));
    if (c == 0) {
#pragma unroll
      for (int mt = 0; mt < 2; mt++)
#pragma unroll
        for (int rg = 0; rg < 4; rg++)
          red_max[mt*16 + q*4 + rg][w] = lm[mt][rg];
    }
    __syncthreads();

    // ---- exp, P_s write, partial row sums ----
    float ps[2][4];
#pragma unroll
    for (int mt = 0; mt < 2; mt++)
#pragma unroll
      for (int rg = 0; rg < 4; rg++) {
        int row = mt*16 + q*4 + rg;
        float gm = fmaxf(fmaxf(red_max[row][0], red_max[row][1]),
                         fmaxf(red_max[row][2], red_max[row][3]));
        float sum = 0.f;
#pragma unroll
        for (int nt = 0; nt < 4; nt++) {
          float e = __expf(acc[mt*4+nt][rg] - gm);
          sum += e;
          P_s[row * kPPitch + w*64 + nt*16 + c] = f2h(e);
        }
        ps[mt][rg] = sum;
      }
#pragma unroll
    for (int s = 1; s < 16; s <<= 1)
#pragma unroll
      for (int mt = 0; mt < 2; mt++)
#pragma unroll
        for (int rg = 0; rg < 4; rg++)
          ps[mt][rg] += __shfl_xor(ps[mt][rg], s, 64);
    if (c == 0) {
#pragma unroll
      for (int mt = 0; mt < 2; mt++)
#pragma unroll
        for (int rg = 0; rg < 4; rg++)
          red_sum[mt*16 + q*4 + rg][w] = ps[mt][rg];
    }
    __syncthreads();

    // ---- PV: wave w -> dh cols [w*16, w*16+16), K=256 ----
    f32x4 oacc[2] = {zero4, zero4};
    const unsigned short* vbase = vt_ws + (size_t)(b*2+h) * 64 * 256;
#pragma unroll
    for (int kt = 0; kt < 8; kt++) {
      int koff = kt * 32 + q * 8;
      half8 bf = *(const half8*)(vbase + (size_t)(w*16 + c) * 256 + koff);
      half8 a0 = *(const half8*)(P_s + (0*16 + c) * kPPitch + koff);
      half8 a1 = *(const half8*)(P_s + (1*16 + c) * kPPitch + koff);
      oacc[0] = __builtin_amdgcn_mfma_f32_16x16x32_f16(a0, bf, oacc[0], 0, 0, 0);
      oacc[1] = __builtin_amdgcn_mfma_f32_16x16x32_f16(a1, bf, oacc[1], 0, 0, 0);
    }
#pragma unroll
    for (int mt = 0; mt < 2; mt++)
#pragma unroll
      for (int rg = 0; rg < 4; rg++) {
        int row = mt*16 + q*4 + rg;
        float rinv = 1.0f / (red_sum[row][0] + red_sum[row][1] +
                             red_sum[row][2] + red_sum[row][3]);
        o_hf[((size_t)(b * kHW + px0 + row)) * 128 + h*64 + w*16 + c] =
            f2h(oacc[mt][rg] * rinv);
      }
  }
}

// ---------------- kernel 4: MFMA MLP chain, fp16, M=64 rows (16 px x 4 batch) ----------------
// R6 structure + (a) cross-barrier prefetch of each phase's first B-frags
// (loads issued during prior phase's epilogue; hide L2 latency under barrier),
// (b) T5 setprio(1) around MFMA clusters (2 desynced blocks/CU -> role diversity).
constexpr int kPitch = 264;   // fp16 LDS pitch

template <int KD>
__device__ __forceinline__ void prefetchB(
    const unsigned short* wt, int c, int q, half8 pre[4])
{
#pragma unroll
  for (int nt = 0; nt < 4; nt++)
    pre[nt] = *(const half8*)(wt + (nt * 16 + c) * KD + q * 8);
}

template <int KD>
__device__ __forceinline__ void gemm4p(
    const unsigned short* abuf, const unsigned short* wt,
    f32x4* acc /*[4*4]*/, int c, int q, const half8 pre[4])
{
#pragma unroll
  for (int ks = 0; ks < KD / 32; ks++) {
    int koff = ks * 32 + q * 8;
    half8 bfr[4];
    if (ks == 0) {
#pragma unroll
      for (int nt = 0; nt < 4; nt++) bfr[nt] = pre[nt];
    } else {
#pragma unroll
      for (int nt = 0; nt < 4; nt++)
        bfr[nt] = *(const half8*)(wt + (nt * 16 + c) * KD + koff);
    }
    half8 afr[4];
#pragma unroll
    for (int mt = 0; mt < 4; mt++)
      afr[mt] = *(const half8*)(abuf + (mt * 16 + c) * kPitch + koff);
    __builtin_amdgcn_s_setprio(1);
#pragma unroll
    for (int mt = 0; mt < 4; mt++)
#pragma unroll
      for (int nt = 0; nt < 4; nt++)
        acc[mt * 4 + nt] = __builtin_amdgcn_mfma_f32_16x16x32_f16(afr[mt], bfr[nt], acc[mt * 4 + nt], 0, 0, 0);
    __builtin_amdgcn_s_setprio(0);
  }
}

__global__ __launch_bounds__(256, 2) void mlp_kernel(
    const unsigned short* __restrict__ o_hf,
    const unsigned short* __restrict__ h0_hf, const unsigned short* __restrict__ h1_hf,
    const unsigned short* __restrict__ tooWt, const float* __restrict__ toob,
    const unsigned short* __restrict__ modW0t, const float* __restrict__ modb0,
    const unsigned short* __restrict__ modW1t, const float* __restrict__ modb1,
    const unsigned short* __restrict__ hvW0t, const float* __restrict__ hvb0,
    const float* __restrict__ outW0, const float* __restrict__ outb0,
    const float* __restrict__ outW1, const float* __restrict__ outb1,
    float* __restrict__ dout)
{
  __shared__ __align__(16) unsigned short buf0[64 * kPitch];  // o, then m0 (hv0)
  __shared__ __align__(16) unsigned short buf1[64 * kPitch];  // mod, then S
  __shared__ __align__(16) unsigned short hbuf[16 * kPitch];  // h0, then h1 (per-pixel)
  __shared__ __align__(16) float scratch[64 * 3 * 4];         // out partials [row][k][wave]

  int tid = threadIdx.x;
  int px0 = blockIdx.x * 16;
  int w = tid >> 6, ln = tid & 63;
  int c = ln & 15, q = ln >> 4;

  const unsigned short* wt1 = tooWt  + (size_t)w * 64 * 128;
  const unsigned short* wt2 = modW0t + (size_t)w * 64 * 256;
  const unsigned short* wt3 = modW1t + (size_t)w * 64 * 256;
  const unsigned short* wt4 = hvW0t  + (size_t)w * 64 * 256;

  // prefetch P1's first B-step before staging (independent of LDS)
  half8 pre[4];
  prefetchB<128>(wt1, c, q, pre);

  // ---- stage o (64 rows x 128) and h0 (16 px x 256) ----
#pragma unroll
  for (int i = 0; i < 4; i++) {
    int idx = i * 256 + tid;              // 1024 x uint4 (8 fp16)
    int r = idx >> 4, c8 = (idx & 15) * 8;
    int b = r >> 4, px = r & 15;
    uint4 v = *(const uint4*)(o_hf + ((size_t)(b * kHW + px0 + px)) * 128 + c8);
    *(uint4*)&buf0[r * kPitch + c8] = v;
  }
#pragma unroll
  for (int i = 0; i < 2; i++) {
    int idx = i * 256 + tid;              // 512 x uint4
    int p = idx >> 5, c8 = (idx & 31) * 8;
    uint4 v = *(const uint4*)(h0_hf + ((size_t)(px0 + p)) * 256 + c8);
    *(uint4*)&hbuf[p * kPitch + c8] = v;
  }
  __syncthreads();

  f32x4 acc[16];
  const f32x4 zero4 = {0.f, 0.f, 0.f, 0.f};

  // ---- P1: mod = o @ tooW + toob -> buf1 ----
#pragma unroll
  for (int i = 0; i < 16; i++) acc[i] = zero4;
  gemm4p<128>(buf0, wt1, acc, c, q, pre);
  prefetchB<256>(wt2, c, q, pre);   // P2 weights: load during P1 epilogue
  {
    float bias[4];
#pragma unroll
    for (int nt = 0; nt < 4; nt++) bias[nt] = toob[w * 64 + nt * 16 + c];
#pragma unroll
    for (int mt = 0; mt < 4; mt++)
#pragma unroll
      for (int nt = 0; nt < 4; nt++)
#pragma unroll
        for (int rg = 0; rg < 4; rg++) {
          int row = mt * 16 + q * 4 + rg, col = w * 64 + nt * 16 + c;
          buf1[row * kPitch + col] = f2h(acc[mt * 4 + nt][rg] + bias[nt]);
        }
  }
  __syncthreads();   // barrier A: mod ready; all o reads done

  // ---- P2: m0 = relu(h0 + mod @ modW0 + b) -> buf0 ----
#pragma unroll
  for (int i = 0; i < 16; i++) acc[i] = zero4;
  gemm4p<256>(buf1, wt2, acc, c, q, pre);
  prefetchB<256>(wt3, c, q, pre);   // P3 weights
  {
    float bias[4], hr[4][4];
#pragma unroll
    for (int nt = 0; nt < 4; nt++) {
      int col = w * 64 + nt * 16 + c;
      bias[nt] = modb0[col];
#pragma unroll
      for (int rg = 0; rg < 4; rg++)
        hr[nt][rg] = h2f(hbuf[(q * 4 + rg) * kPitch + col]);
    }
#pragma unroll
    for (int mt = 0; mt < 4; mt++)
#pragma unroll
      for (int nt = 0; nt < 4; nt++)
#pragma unroll
        for (int rg = 0; rg < 4; rg++) {
          int row = mt * 16 + q * 4 + rg, col = w * 64 + nt * 16 + c;
          buf0[row * kPitch + col] =
              f2h(fmaxf(acc[mt * 4 + nt][rg] + bias[nt] + hr[nt][rg], 0.f));
        }
  }
  __syncthreads();   // barrier B: h0 consumed, m0 in buf0

  // ---- P3: stage h1; m1 = relu(h1 + mod @ modW1 + b); S = m0 + m1 -> buf1 ----
#pragma unroll
  for (int i = 0; i < 2; i++) {
    int idx = i * 256 + tid;
    int p = idx >> 5, c8 = (idx & 31) * 8;
    uint4 v = *(const uint4*)(h1_hf + ((size_t)(px0 + p)) * 256 + c8);
    *(uint4*)&hbuf[p * kPitch + c8] = v;
  }
#pragma unroll
  for (int i = 0; i < 16; i++) acc[i] = zero4;
  gemm4p<256>(buf1, wt3, acc, c, q, pre);
  prefetchB<256>(wt4, c, q, pre);   // P4 weights
  __syncthreads();   // barrier C: h1 staged AND all mod reads done
  {
    float bias[4], hr[4][4];
#pragma unroll
    for (int nt = 0; nt < 4; nt++) {
      int col = w * 64 + nt * 16 + c;
      bias[nt] = modb1[col];
#pragma unroll
      for (int rg = 0; rg < 4; rg++)
        hr[nt][rg] = h2f(hbuf[(q * 4 + rg) * kPitch + col]);
    }
#pragma unroll
    for (int mt = 0; mt < 4; mt++)
#pragma unroll
      for (int nt = 0; nt < 4; nt++)
#pragma unroll
        for (int rg = 0; rg < 4; rg++) {
          int row = mt * 16 + q * 4 + rg, col = w * 64 + nt * 16 + c;
          float m0v = h2f(buf0[row * kPitch + col]);
          float v = m0v + fmaxf(acc[mt * 4 + nt][rg] + bias[nt] + hr[nt][rg], 0.f);
          buf1[row * kPitch + col] = f2h(v);
        }
  }
  __syncthreads();   // barrier D: S ready

  // ---- P4: hv1 = relu(S @ hvW0 + b); fused out epilogue ----
#pragma unroll
  for (int i = 0; i < 16; i++) acc[i] = zero4;
  gemm4p<256>(buf1, wt4, acc, c, q, pre);
  {
    float bias[4], w0v[4][3], w1v[4][3];
#pragma unroll
    for (int nt = 0; nt < 4; nt++) {
      int col = w * 64 + nt * 16 + c;
      bias[nt] = hvb0[col];
#pragma unroll
      for (int k = 0; k < 3; k++) {
        w0v[nt][k] = outW0[col * 3 + k];
        w1v[nt][k] = outW1[col * 3 + k];
      }
    }
#pragma unroll
    for (int mt = 0; mt < 4; mt++) {
      float pk[4][3];
#pragma unroll
      for (int rg = 0; rg < 4; rg++)
#pragma unroll
        for (int k = 0; k < 3; k++) pk[rg][k] = 0.f;
#pragma unroll
      for (int nt = 0; nt < 4; nt++) {
        int col = w * 64 + nt * 16 + c;
#pragma unroll
        for (int rg = 0; rg < 4; rg++) {
          int row = mt * 16 + q * 4 + rg;
          float hv1 = fmaxf(acc[mt * 4 + nt][rg] + bias[nt], 0.f);
          float m0v = h2f(buf0[row * kPitch + col]);
#pragma unroll
          for (int k = 0; k < 3; k++)
            pk[rg][k] += m0v * w0v[nt][k] + hv1 * w1v[nt][k];
        }
      }
#pragma unroll
      for (int s = 1; s < 16; s <<= 1)
#pragma unroll
        for (int rg = 0; rg < 4; rg++)
#pragma unroll
          for (int k = 0; k < 3; k++)
            pk[rg][k] += __shfl_xor(pk[rg][k], s, 64);
      if (c == 0) {
#pragma unroll
        for (int rg = 0; rg < 4; rg++) {
          int row = mt * 16 + q * 4 + rg;
#pragma unroll
          for (int k = 0; k < 3; k++)
            scratch[row * 12 + k * 4 + w] = pk[rg][k];
        }
      }
    }
  }
  __syncthreads();

  if (tid < 192) {
    int row = tid / 3, k = tid % 3;
    int b = row >> 4, px = px0 + (row & 15);
    float s = outb0[k] + outb1[k];
#pragma unroll
    for (int ww = 0; ww < 4; ww++) s += scratch[row * 12 + k * 4 + ww];
    dout[((size_t)b * kHW + px) * 3 + k] = s;
  }
}

// ---------------- launch ----------------
extern "C" void kernel_launch(void* const* d_in, const int* in_sizes, int n_in,
                              void* d_out, int out_size, void* d_ws, size_t ws_size,
                              hipStream_t stream) {
  const float* coords = (const float*)d_in[0];
  const float* tokens = (const float*)d_in[1];
  const float* Bq     = (const float*)d_in[2];
  const float* Bl0    = (const float*)d_in[3];
  const float* Bl1    = (const float*)d_in[4];
  const float* qW     = (const float*)d_in[5];
  const float* qb     = (const float*)d_in[6];
  const float* toqW   = (const float*)d_in[7];
  const float* tokvW  = (const float*)d_in[8];
  const float* tooW   = (const float*)d_in[9];
  const float* toob   = (const float*)d_in[10];
  const float* bwW0   = (const float*)d_in[11];
  const float* bwb0   = (const float*)d_in[12];
  const float* bwW1   = (const float*)d_in[13];
  const float* bwb1   = (const float*)d_in[14];
  const float* modW0  = (const float*)d_in[15];
  const float* modb0  = (const float*)d_in[16];
  const float* modW1  = (const float*)d_in[17];
  const float* modb1  = (const float*)d_in[18];
  const float* hvW0   = (const float*)d_in[19];
  const float* hvb0   = (const float*)d_in[20];
  const float* outW0  = (const float*)d_in[21];
  const float* outb0  = (const float*)d_in[22];
  const float* outW1  = (const float*)d_in[23];
  const float* outb1  = (const float*)d_in[24];

  char* ws = (char*)d_ws;
  float*          t_ws   = (float*)(ws + 0);                  //   64 KB
  unsigned short* qc_ws  = (unsigned short*)(ws + 65536);     //    4 MB
  unsigned short* h0_hf  = (unsigned short*)(ws + 4259840);   //    8 MB
  unsigned short* h1_hf  = (unsigned short*)(ws + 12648448);  //    8 MB
  unsigned short* o_hf   = (unsigned short*)(ws + 21037056);  //   16 MB
  unsigned short* kn_ws  = (unsigned short*)(ws + 37814272);  //  256 KB
  unsigned short* vt_ws  = (unsigned short*)(ws + 38076416);  //  256 KB
  unsigned short* tooWt  = (unsigned short*)(ws + 38338560);  //   64 KB
  unsigned short* modW0t = (unsigned short*)(ws + 38404096);  //  128 KB
  unsigned short* modW1t = (unsigned short*)(ws + 38535168);  //  128 KB
  unsigned short* hvW0t  = (unsigned short*)(ws + 38666240);  //  128 KB
  unsigned short* qWt    = (unsigned short*)(ws + 38797312);  //   32 KB
  unsigned short* bw0t   = (unsigned short*)(ws + 38830080);  //   32 KB
  unsigned short* bw1t   = (unsigned short*)(ws + 38862848);  //   32 KB
  unsigned short* toqWt  = (unsigned short*)(ws + 38895616);  //   64 KB

  prep_kernel<<<dim3(kB * kM + 64), 256, 0, stream>>>(
      tokens, tokvW, kn_ws, vt_ws,
      tooW, modW0, modW1, hvW0, qW, bwW0, bwW1, toqW,
      tooWt, modW0t, modW1t, hvW0t, qWt, bw0t, bw1t, toqWt);
  feat_kernel<<<dim3(kHW / 32), 256, 0, stream>>>(
      coords, Bq, Bl0, Bl1, qb, bwb0, bwb1,
      qWt, bw0t, bw1t, toqWt,
      t_ws, qc_ws, h0_hf, h1_hf);
  attn_kernel<<<dim3(kHW / 32, kB), 256, 0, stream>>>(kn_ws, vt_ws, qc_ws, t_ws, o_hf);
  mlp_kernel<<<dim3(kHW / 16), 256, 0, stream>>>(
      o_hf, h0_hf, h1_hf, tooWt, toob, modW0t, modb0, modW1t, modb1,
      hvW0t, hvb0, outW0, outb0, outW1, outb1, (float*)d_out);
}

// Round 11
// 236.263 us; speedup vs baseline: 1.2141x; 1.0189x over previous
//
#include <hip/hip_runtime.h>
#include <stdint.h>

constexpr int kHW = 16384;   // 128*128 pixels (grid shared across batch)
constexpr int kB  = 4;
constexpr int kM  = 256;     // tokens

typedef _Float16 half8 __attribute__((ext_vector_type(8)));  // 8 fp16 (4 VGPRs)
typedef __attribute__((ext_vector_type(4))) float f32x4;     // MFMA accum

// ---------------- helpers ----------------
__device__ __forceinline__ unsigned short f2h(float f) {
  _Float16 h = (_Float16)f;
  return __builtin_bit_cast(unsigned short, h);
}
__device__ __forceinline__ float h2f(unsigned short u) {
  return (float)__builtin_bit_cast(_Float16, u);
}

// ---------------- kernel 0: prep = wprep (64 blocks) + kv (1024 blocks), one launch ----------------
__global__ __launch_bounds__(256) void prep_kernel(
    const float* __restrict__ tokens, const float* __restrict__ tokvW,
    unsigned short* __restrict__ kn_ws, unsigned short* __restrict__ vt_ws,
    const float* __restrict__ tooW, const float* __restrict__ modW0,
    const float* __restrict__ modW1, const float* __restrict__ hvW0,
    const float* __restrict__ qW, const float* __restrict__ bwW0,
    const float* __restrict__ bwW1, const float* __restrict__ toqW,
    unsigned short* __restrict__ tooWt, unsigned short* __restrict__ modW0t,
    unsigned short* __restrict__ modW1t, unsigned short* __restrict__ hvW0t,
    unsigned short* __restrict__ qWt, unsigned short* __restrict__ bw0t,
    unsigned short* __restrict__ bw1t, unsigned short* __restrict__ toqWt)
{
  __shared__ __align__(16) float tok[256];
  int bx = blockIdx.x, tid = threadIdx.x;

  if (bx < kB * kM) {
    // ---- kv part ----
    int b = bx >> 8, j = bx & 255, c = tid;
    tok[c] = tokens[(b * kM + j) * 256 + c];
    __syncthreads();
    float acc = 0.f;
    for (int i4 = 0; i4 < 64; i4++) {
      float4 t4 = *(const float4*)&tok[i4 * 4];
      acc += t4.x * tokvW[(i4*4+0)*256 + c] + t4.y * tokvW[(i4*4+1)*256 + c]
           + t4.z * tokvW[(i4*4+2)*256 + c] + t4.w * tokvW[(i4*4+3)*256 + c];
    }
    unsigned short hv = f2h(acc);
    if (c < 128) {
      int h = c >> 6, dd = c & 63;
      kn_ws[((size_t)(b*2+h)*256 + j) * 64 + dd] = hv;
    } else {
      int c2 = c - 128;
      int h = c2 >> 6, dd = c2 & 63;
      vt_ws[((size_t)(b*2+h)*64 + dd) * 256 + j] = hv;
    }
  } else {
    // ---- wprep part: block t -> (matrix m, K-chunk ch of 8) ----
    int t = bx - kB * kM;          // 0..63
    int m = t >> 3, ch = t & 7;
    const float* Ws[8] = {tooW, modW0, modW1, hvW0, qW, bwW0, bwW1, toqW};
    unsigned short* Wts[8] = {tooWt, modW0t, modW1t, hvW0t, qWt, bw0t, bw1t, toqWt};
    const int Ks[8] = {128, 256, 256, 256, 64, 64, 64, 256};
    const int Ns[8] = {256, 256, 256, 256, 256, 256, 256, 128};
    const float* W = Ws[m];
    unsigned short* Wt = Wts[m];
    int K = Ks[m], N = Ns[m];
    int nkb = K / 8;               // 8, 16 or 32
    int per = nkb >> 3;            // 1, 2 or 4 iters per block
    int kb0 = ch * per;
    if (tid < N) {
      for (int kb = kb0; kb < kb0 + per; kb++) {
        unsigned short sv[8];
#pragma unroll
        for (int i = 0; i < 8; i++)
          sv[i] = f2h(W[(kb * 8 + i) * N + tid]);   // coalesced across tid
        *(uint4*)&Wt[tid * K + kb * 8] = *(const uint4*)sv;
      }
    }
  }
}

// ---------------- kernel 2: MFMA per-pixel features (shared across batch) ----------------
// + cross-barrier first-step weight prefetch (proven on mlp, R10) + setprio.
constexpr int kFPitch = 72;    // fp16 pitch for ff rows (144 B = 9*16)
constexpr int kXPitch = 264;   // fp16 pitch for xq rows

__global__ __launch_bounds__(256, 2) void feat_kernel(
    const float* __restrict__ coords,
    const float* __restrict__ Bq, const float* __restrict__ Bl0, const float* __restrict__ Bl1,
    const float* __restrict__ qb, const float* __restrict__ bwb0, const float* __restrict__ bwb1,
    const unsigned short* __restrict__ qWt, const unsigned short* __restrict__ bw0t,
    const unsigned short* __restrict__ bw1t, const unsigned short* __restrict__ toqWt,
    float* __restrict__ t_ws, unsigned short* __restrict__ qc_ws,
    unsigned short* __restrict__ h0_hf, unsigned short* __restrict__ h1_hf)
{
  __shared__ __align__(16) unsigned short ff_s[3][32][kFPitch];
  __shared__ __align__(16) unsigned short xq_s[32][kXPitch];
  __shared__ float coords_s[64];

  int tid = threadIdx.x;
  int px0 = blockIdx.x * 32;
  int w = tid >> 6, ln = tid & 63;
  int c = ln & 15, q = ln >> 4;

  if (tid < 64) coords_s[tid] = coords[px0 * 2 + tid];
  __syncthreads();

  // prefetch mat0 (qWt) first K-step -- hides under the sincos block below
  half8 bpre[4];
#pragma unroll
  for (int nt = 0; nt < 4; nt++)
    bpre[nt] = *(const half8*)(qWt + (size_t)(w*64 + nt*16 + c) * 64 + q * 8);

  // ---- Fourier features: 3 mats * 32 px * 64 f = 6144 vals, 24/thread ----
#pragma unroll
  for (int r = 0; r < 24; r++) {
    int v = r * 256 + tid;
    int mat = v >> 11;
    int p = (v >> 6) & 31;
    int f = v & 63;
    int fr = f & 31;
    const float* Bm = (mat == 0) ? Bq : (mat == 1 ? Bl0 : Bl1);
    float x = coords_s[p * 2 + 0];
    float y = coords_s[p * 2 + 1];
    float proj = 6.283185307179586f * (x * Bm[fr*2+0] + y * Bm[fr*2+1]);
    float s, cc;
    __sincosf(proj, &s, &cc);
    ff_s[mat][p][f] = f2h((f < 32) ? cc : s);
  }
  if (tid < 32) {
    float x = coords_s[tid * 2 + 0];
    float y = coords_s[tid * 2 + 1];
    int row = min(max((int)(x * 16.0f), 0), 15);
    int col = min(max((int)(y * 16.0f), 0), 15);
    t_ws[px0 + tid] = (float)(row * 16 + col) * (1.0f / 256.0f);
  }
  __syncthreads();

  const f32x4 zero4 = {0.f, 0.f, 0.f, 0.f};

  // ---- 3 GEMMs: M=32, N=256 (wave owns 64 cols), K=64 ----
#pragma unroll
  for (int mat = 0; mat < 3; mat++) {
    const unsigned short* Wt = (mat == 0) ? qWt : (mat == 1 ? bw0t : bw1t);
    const float* bias = (mat == 0) ? qb : (mat == 1 ? bwb0 : bwb1);
    f32x4 acc[8];
#pragma unroll
    for (int i = 0; i < 8; i++) acc[i] = zero4;
#pragma unroll
    for (int ks = 0; ks < 2; ks++) {
      int koff = ks * 32 + q * 8;
      half8 bfr[4];
      if (ks == 0) {
#pragma unroll
        for (int nt = 0; nt < 4; nt++) bfr[nt] = bpre[nt];
      } else {
#pragma unroll
        for (int nt = 0; nt < 4; nt++)
          bfr[nt] = *(const half8*)(Wt + (size_t)(w*64 + nt*16 + c) * 64 + koff);
      }
      half8 afr[2];
#pragma unroll
      for (int mt = 0; mt < 2; mt++)
        afr[mt] = *(const half8*)(&ff_s[mat][mt*16 + c][koff]);
      __builtin_amdgcn_s_setprio(1);
#pragma unroll
      for (int mt = 0; mt < 2; mt++)
#pragma unroll
        for (int nt = 0; nt < 4; nt++)
          acc[mt*4+nt] = __builtin_amdgcn_mfma_f32_16x16x32_f16(afr[mt], bfr[nt], acc[mt*4+nt], 0, 0, 0);
      __builtin_amdgcn_s_setprio(0);
    }
    // chain-prefetch next mat's first K-step (hides under this epilogue)
    if (mat == 0) {
#pragma unroll
      for (int nt = 0; nt < 4; nt++)
        bpre[nt] = *(const half8*)(bw0t + (size_t)(w*64 + nt*16 + c) * 64 + q * 8);
    } else if (mat == 1) {
#pragma unroll
      for (int nt = 0; nt < 4; nt++)
        bpre[nt] = *(const half8*)(bw1t + (size_t)(w*64 + nt*16 + c) * 64 + q * 8);
    }
    float bv[4];
#pragma unroll
    for (int nt = 0; nt < 4; nt++) bv[nt] = bias[w*64 + nt*16 + c];
#pragma unroll
    for (int mt = 0; mt < 2; mt++)
#pragma unroll
      for (int nt = 0; nt < 4; nt++)
#pragma unroll
        for (int rg = 0; rg < 4; rg++) {
          int row = mt*16 + q*4 + rg, col = w*64 + nt*16 + c;
          unsigned short hv = f2h(fmaxf(acc[mt*4+nt][rg] + bv[nt], 0.f));
          if (mat == 0)      xq_s[row][col] = hv;
          else if (mat == 1) h0_hf[((size_t)(px0 + row)) * 256 + col] = hv;
          else               h1_hf[((size_t)(px0 + row)) * 256 + col] = hv;
        }
  }
  // prefetch q-GEMM (toqWt) first K-step before the barrier
  half8 qpre[2];
#pragma unroll
  for (int nt = 0; nt < 2; nt++)
    qpre[nt] = *(const half8*)(toqWt + (size_t)(w*32 + nt*16 + c) * 256 + q * 8);
  __syncthreads();   // xq_s ready

  // ---- q GEMM: M=32, N=128 (wave owns 32 cols), K=256, no bias ----
  {
    f32x4 acc2[4];
#pragma unroll
    for (int i = 0; i < 4; i++) acc2[i] = zero4;
#pragma unroll
    for (int kt = 0; kt < 8; kt++) {
      int koff = kt * 32 + q * 8;
      half8 bfr[2];
      if (kt == 0) {
#pragma unroll
        for (int nt = 0; nt < 2; nt++) bfr[nt] = qpre[nt];
      } else {
#pragma unroll
        for (int nt = 0; nt < 2; nt++)
          bfr[nt] = *(const half8*)(toqWt + (size_t)(w*32 + nt*16 + c) * 256 + koff);
      }
      half8 afr[2];
#pragma unroll
      for (int mt = 0; mt < 2; mt++)
        afr[mt] = *(const half8*)(&xq_s[mt*16 + c][koff]);
      __builtin_amdgcn_s_setprio(1);
#pragma unroll
      for (int mt = 0; mt < 2; mt++)
#pragma unroll
        for (int nt = 0; nt < 2; nt++)
          acc2[mt*2+nt] = __builtin_amdgcn_mfma_f32_16x16x32_f16(afr[mt], bfr[nt], acc2[mt*2+nt], 0, 0, 0);
      __builtin_amdgcn_s_setprio(0);
    }
#pragma unroll
    for (int mt = 0; mt < 2; mt++)
#pragma unroll
      for (int nt = 0; nt < 2; nt++)
#pragma unroll
        for (int rg = 0; rg < 4; rg++) {
          int row = mt*16 + q*4 + rg, col = w*32 + nt*16 + c;
          qc_ws[((size_t)(px0 + row)) * 128 + col] = f2h(acc2[mt*2+nt][rg]);
        }
  }
}

// ---------------- kernel 3: MFMA cross attention with spatial bias (fp16) ----------------
// + cross-barrier K/V first-step prefetch + setprio (same mechanism as mlp R10).
constexpr int kPPitch = 264;

__global__ __launch_bounds__(256, 2) void attn_kernel(
    const unsigned short* __restrict__ kn_ws,
    const unsigned short* __restrict__ vt_ws,
    const unsigned short* __restrict__ qc_ws,
    const float* __restrict__ t_ws,
    unsigned short* __restrict__ o_hf)
{
  __shared__ __align__(16) unsigned short P_s[32 * kPPitch];
  __shared__ float t_s[32];
  __shared__ float red_max[32][4];
  __shared__ float red_sum[32][4];

  int b = blockIdx.y;
  int px0 = blockIdx.x * 32;
  int tid = threadIdx.x;
  int w = tid >> 6, ln = tid & 63;
  int c = ln & 15, q = ln >> 4;

  if (tid < 32) t_s[tid] = t_ws[px0 + tid];

  const f32x4 zero4 = {0.f, 0.f, 0.f, 0.f};

  // prefetch h=0's K first-step
  half8 kpre[4];
  {
    const unsigned short* kb = kn_ws + (size_t)(b*2) * 256 * 64;
#pragma unroll
    for (int nt = 0; nt < 4; nt++)
      kpre[nt] = *(const half8*)(kb + (size_t)(w*64 + nt*16 + c) * 64 + q * 8);
  }

#pragma unroll
  for (int h = 0; h < 2; h++) {
    __syncthreads();

    // ---- QK^T: M=32, N=256 (wave strip of 64), K=64 ----
    f32x4 acc[8];
#pragma unroll
    for (int i = 0; i < 8; i++) acc[i] = zero4;
    const unsigned short* kbase = kn_ws + (size_t)(b*2+h) * 256 * 64;
#pragma unroll
    for (int ks = 0; ks < 2; ks++) {
      int koff = ks * 32 + q * 8;
      half8 a0 = *(const half8*)(qc_ws + (size_t)(px0 + c) * 128 + h*64 + koff);
      half8 a1 = *(const half8*)(qc_ws + (size_t)(px0 + 16 + c) * 128 + h*64 + koff);
      half8 bf[4];
      if (ks == 0) {
#pragma unroll
        for (int nt = 0; nt < 4; nt++) bf[nt] = kpre[nt];
      } else {
#pragma unroll
        for (int nt = 0; nt < 4; nt++)
          bf[nt] = *(const half8*)(kbase + (size_t)(w*64 + nt*16 + c) * 64 + koff);
      }
      __builtin_amdgcn_s_setprio(1);
#pragma unroll
      for (int nt = 0; nt < 4; nt++) {
        acc[0*4+nt] = __builtin_amdgcn_mfma_f32_16x16x32_f16(a0, bf[nt], acc[0*4+nt], 0, 0, 0);
        acc[1*4+nt] = __builtin_amdgcn_mfma_f32_16x16x32_f16(a1, bf[nt], acc[1*4+nt], 0, 0, 0);
      }
      __builtin_amdgcn_s_setprio(0);
    }

    // prefetch V first-step (hides under softmax + 2 barriers)
    const unsigned short* vbase = vt_ws + (size_t)(b*2+h) * 64 * 256;
    half8 vpre = *(const half8*)(vbase + (size_t)(w*16 + c) * 256 + q * 8);

    // ---- bias + scale, per-lane row max ----
    float lm[2][4];
#pragma unroll
    for (int mt = 0; mt < 2; mt++)
#pragma unroll
      for (int rg = 0; rg < 4; rg++) {
        int row = mt*16 + q*4 + rg;
        float tv = t_s[row];
        float mx = -1e30f;
#pragma unroll
        for (int nt = 0; nt < 4; nt++) {
          int token = w*64 + nt*16 + c;
          float pos = ((float)token + 0.5f) * (1.0f / 256.0f);
          float db = tv - pos;
          float sb = acc[mt*4+nt][rg] * 0.125f - 10.0f * db * db;
          acc[mt*4+nt][rg] = sb;
          mx = fmaxf(mx, sb);
        }
        lm[mt][rg] = mx;
      }
#pragma unroll
    for (int s = 1; s < 16; s <<= 1)
#pragma unroll
      for (int mt = 0; mt < 2; mt++)
#pragma unroll
        for (int rg = 0; rg < 4; rg++)
          lm[mt][rg] = fmaxf(lm[mt][rg], __shfl_xor(lm[mt][rg], s, 64));
    if (c == 0) {
#pragma unroll
      for (int mt = 0; mt < 2; mt++)
#pragma unroll
        for (int rg = 0; rg < 4; rg++)
          red_max[mt*16 + q*4 + rg][w] = lm[mt][rg];
    }
    __syncthreads();

    // ---- exp, P_s write, partial row sums ----
    float ps[2][4];
#pragma unroll
    for (int mt = 0; mt < 2; mt++)
#pragma unroll
      for (int rg = 0; rg < 4; rg++) {
        int row = mt*16 + q*4 + rg;
        float gm = fmaxf(fmaxf(red_max[row][0], red_max[row][1]),
                         fmaxf(red_max[row][2], red_max[row][3]));
        float sum = 0.f;
#pragma unroll
        for (int nt = 0; nt < 4; nt++) {
          float e = __expf(acc[mt*4+nt][rg] - gm);
          sum += e;
          P_s[row * kPPitch + w*64 + nt*16 + c] = f2h(e);
        }
        ps[mt][rg] = sum;
      }
#pragma unroll
    for (int s = 1; s < 16; s <<= 1)
#pragma unroll
      for (int mt = 0; mt < 2; mt++)
#pragma unroll
        for (int rg = 0; rg < 4; rg++)
          ps[mt][rg] += __shfl_xor(ps[mt][rg], s, 64);
    if (c == 0) {
#pragma unroll
      for (int mt = 0; mt < 2; mt++)
#pragma unroll
        for (int rg = 0; rg < 4; rg++)
          red_sum[mt*16 + q*4 + rg][w] = ps[mt][rg];
    }
    __syncthreads();

    // ---- PV: wave w -> dh cols [w*16, w*16+16), K=256 ----
    f32x4 oacc[2] = {zero4, zero4};
#pragma unroll
    for (int kt = 0; kt < 8; kt++) {
      int koff = kt * 32 + q * 8;
      half8 bf = (kt == 0) ? vpre
               : *(const half8*)(vbase + (size_t)(w*16 + c) * 256 + koff);
      half8 a0 = *(const half8*)(P_s + (0*16 + c) * kPPitch + koff);
      half8 a1 = *(const half8*)(P_s + (1*16 + c) * kPPitch + koff);
      __builtin_amdgcn_s_setprio(1);
      oacc[0] = __builtin_amdgcn_mfma_f32_16x16x32_f16(a0, bf, oacc[0], 0, 0, 0);
      oacc[1] = __builtin_amdgcn_mfma_f32_16x16x32_f16(a1, bf, oacc[1], 0, 0, 0);
      __builtin_amdgcn_s_setprio(0);
    }
    // prefetch h=1's K first-step during this epilogue
    if (h == 0) {
      const unsigned short* kb1 = kn_ws + (size_t)(b*2+1) * 256 * 64;
#pragma unroll
      for (int nt = 0; nt < 4; nt++)
        kpre[nt] = *(const half8*)(kb1 + (size_t)(w*64 + nt*16 + c) * 64 + q * 8);
    }
#pragma unroll
    for (int mt = 0; mt < 2; mt++)
#pragma unroll
      for (int rg = 0; rg < 4; rg++) {
        int row = mt*16 + q*4 + rg;
        float rinv = 1.0f / (red_sum[row][0] + red_sum[row][1] +
                             red_sum[row][2] + red_sum[row][3]);
        o_hf[((size_t)(b * kHW + px0 + row)) * 128 + h*64 + w*16 + c] =
            f2h(oacc[mt][rg] * rinv);
      }
  }
}

// ---------------- kernel 4: MFMA MLP chain (R10 verbatim: prefetch + setprio, banked) ----------------
constexpr int kPitch = 264;   // fp16 LDS pitch

template <int KD>
__device__ __forceinline__ void prefetchB(
    const unsigned short* wt, int c, int q, half8 pre[4])
{
#pragma unroll
  for (int nt = 0; nt < 4; nt++)
    pre[nt] = *(const half8*)(wt + (nt * 16 + c) * KD + q * 8);
}

template <int KD>
__device__ __forceinline__ void gemm4p(
    const unsigned short* abuf, const unsigned short* wt,
    f32x4* acc /*[4*4]*/, int c, int q, const half8 pre[4])
{
#pragma unroll
  for (int ks = 0; ks < KD / 32; ks++) {
    int koff = ks * 32 + q * 8;
    half8 bfr[4];
    if (ks == 0) {
#pragma unroll
      for (int nt = 0; nt < 4; nt++) bfr[nt] = pre[nt];
    } else {
#pragma unroll
      for (int nt = 0; nt < 4; nt++)
        bfr[nt] = *(const half8*)(wt + (nt * 16 + c) * KD + koff);
    }
    half8 afr[4];
#pragma unroll
    for (int mt = 0; mt < 4; mt++)
      afr[mt] = *(const half8*)(abuf + (mt * 16 + c) * kPitch + koff);
    __builtin_amdgcn_s_setprio(1);
#pragma unroll
    for (int mt = 0; mt < 4; mt++)
#pragma unroll
      for (int nt = 0; nt < 4; nt++)
        acc[mt * 4 + nt] = __builtin_amdgcn_mfma_f32_16x16x32_f16(afr[mt], bfr[nt], acc[mt * 4 + nt], 0, 0, 0);
    __builtin_amdgcn_s_setprio(0);
  }
}

__global__ __launch_bounds__(256, 2) void mlp_kernel(
    const unsigned short* __restrict__ o_hf,
    const unsigned short* __restrict__ h0_hf, const unsigned short* __restrict__ h1_hf,
    const unsigned short* __restrict__ tooWt, const float* __restrict__ toob,
    const unsigned short* __restrict__ modW0t, const float* __restrict__ modb0,
    const unsigned short* __restrict__ modW1t, const float* __restrict__ modb1,
    const unsigned short* __restrict__ hvW0t, const float* __restrict__ hvb0,
    const float* __restrict__ outW0, const float* __restrict__ outb0,
    const float* __restrict__ outW1, const float* __restrict__ outb1,
    float* __restrict__ dout)
{
  __shared__ __align__(16) unsigned short buf0[64 * kPitch];  // o, then m0 (hv0)
  __shared__ __align__(16) unsigned short buf1[64 * kPitch];  // mod, then S
  __shared__ __align__(16) unsigned short hbuf[16 * kPitch];  // h0, then h1 (per-pixel)
  __shared__ __align__(16) float scratch[64 * 3 * 4];         // out partials [row][k][wave]

  int tid = threadIdx.x;
  int px0 = blockIdx.x * 16;
  int w = tid >> 6, ln = tid & 63;
  int c = ln & 15, q = ln >> 4;

  const unsigned short* wt1 = tooWt  + (size_t)w * 64 * 128;
  const unsigned short* wt2 = modW0t + (size_t)w * 64 * 256;
  const unsigned short* wt3 = modW1t + (size_t)w * 64 * 256;
  const unsigned short* wt4 = hvW0t  + (size_t)w * 64 * 256;

  // prefetch P1's first B-step before staging (independent of LDS)
  half8 pre[4];
  prefetchB<128>(wt1, c, q, pre);

  // ---- stage o (64 rows x 128) and h0 (16 px x 256) ----
#pragma unroll
  for (int i = 0; i < 4; i++) {
    int idx = i * 256 + tid;              // 1024 x uint4 (8 fp16)
    int r = idx >> 4, c8 = (idx & 15) * 8;
    int b = r >> 4, px = r & 15;
    uint4 v = *(const uint4*)(o_hf + ((size_t)(b * kHW + px0 + px)) * 128 + c8);
    *(uint4*)&buf0[r * kPitch + c8] = v;
  }
#pragma unroll
  for (int i = 0; i < 2; i++) {
    int idx = i * 256 + tid;              // 512 x uint4
    int p = idx >> 5, c8 = (idx & 31) * 8;
    uint4 v = *(const uint4*)(h0_hf + ((size_t)(px0 + p)) * 256 + c8);
    *(uint4*)&hbuf[p * kPitch + c8] = v;
  }
  __syncthreads();

  f32x4 acc[16];
  const f32x4 zero4 = {0.f, 0.f, 0.f, 0.f};

  // ---- P1: mod = o @ tooW + toob -> buf1 ----
#pragma unroll
  for (int i = 0; i < 16; i++) acc[i] = zero4;
  gemm4p<128>(buf0, wt1, acc, c, q, pre);
  prefetchB<256>(wt2, c, q, pre);   // P2 weights: load during P1 epilogue
  {
    float bias[4];
#pragma unroll
    for (int nt = 0; nt < 4; nt++) bias[nt] = toob[w * 64 + nt * 16 + c];
#pragma unroll
    for (int mt = 0; mt < 4; mt++)
#pragma unroll
      for (int nt = 0; nt < 4; nt++)
#pragma unroll
        for (int rg = 0; rg < 4; rg++) {
          int row = mt * 16 + q * 4 + rg, col = w * 64 + nt * 16 + c;
          buf1[row * kPitch + col] = f2h(acc[mt * 4 + nt][rg] + bias[nt]);
        }
  }
  __syncthreads();   // barrier A: mod ready; all o reads done

  // ---- P2: m0 = relu(h0 + mod @ modW0 + b) -> buf0 ----
#pragma unroll
  for (int i = 0; i < 16; i++) acc[i] = zero4;
  gemm4p<256>(buf1, wt2, acc, c, q, pre);
  prefetchB<256>(wt3, c, q, pre);   // P3 weights
  {
    float bias[4], hr[4][4];
#pragma unroll
    for (int nt = 0; nt < 4; nt++) {
      int col = w * 64 + nt * 16 + c;
      bias[nt] = modb0[col];
#pragma unroll
      for (int rg = 0; rg < 4; rg++)
        hr[nt][rg] = h2f(hbuf[(q * 4 + rg) * kPitch + col]);
    }
#pragma unroll
    for (int mt = 0; mt < 4; mt++)
#pragma unroll
      for (int nt = 0; nt < 4; nt++)
#pragma unroll
        for (int rg = 0; rg < 4; rg++) {
          int row = mt * 16 + q * 4 + rg, col = w * 64 + nt * 16 + c;
          buf0[row * kPitch + col] =
              f2h(fmaxf(acc[mt * 4 + nt][rg] + bias[nt] + hr[nt][rg], 0.f));
        }
  }
  __syncthreads();   // barrier B: h0 consumed, m0 in buf0

  // ---- P3: stage h1; m1 = relu(h1 + mod @ modW1 + b); S = m0 + m1 -> buf1 ----
#pragma unroll
  for (int i = 0; i < 2; i++) {
    int idx = i * 256 + tid;
    int p = idx >> 5, c8 = (idx & 31) * 8;
    uint4 v = *(const uint4*)(h1_hf + ((size_t)(px0 + p)) * 256 + c8);
    *(uint4*)&hbuf[p * kPitch + c8] = v;
  }
#pragma unroll
  for (int i = 0; i < 16; i++) acc[i] = zero4;
  gemm4p<256>(buf1, wt3, acc, c, q, pre);
  prefetchB<256>(wt4, c, q, pre);   // P4 weights
  __syncthreads();   // barrier C: h1 staged AND all mod reads done
  {
    float bias[4], hr[4][4];
#pragma unroll
    for (int nt = 0; nt < 4; nt++) {
      int col = w * 64 + nt * 16 + c;
      bias[nt] = modb1[col];
#pragma unroll
      for (int rg = 0; rg < 4; rg++)
        hr[nt][rg] = h2f(hbuf[(q * 4 + rg) * kPitch + col]);
    }
#pragma unroll
    for (int mt = 0; mt < 4; mt++)
#pragma unroll
      for (int nt = 0; nt < 4; nt++)
#pragma unroll
        for (int rg = 0; rg < 4; rg++) {
          int row = mt * 16 + q * 4 + rg, col = w * 64 + nt * 16 + c;
          float m0v = h2f(buf0[row * kPitch + col]);
          float v = m0v + fmaxf(acc[mt * 4 + nt][rg] + bias[nt] + hr[nt][rg], 0.f);
          buf1[row * kPitch + col] = f2h(v);
        }
  }
  __syncthreads();   // barrier D: S ready

  // ---- P4: hv1 = relu(S @ hvW0 + b); fused out epilogue ----
#pragma unroll
  for (int i = 0; i < 16; i++) acc[i] = zero4;
  gemm4p<256>(buf1, wt4, acc, c, q, pre);
  {
    float bias[4], w0v[4][3], w1v[4][3];
#pragma unroll
    for (int nt = 0; nt < 4; nt++) {
      int col = w * 64 + nt * 16 + c;
      bias[nt] = hvb0[col];
#pragma unroll
      for (int k = 0; k < 3; k++) {
        w0v[nt][k] = outW0[col * 3 + k];
        w1v[nt][k] = outW1[col * 3 + k];
      }
    }
#pragma unroll
    for (int mt = 0; mt < 4; mt++) {
      float pk[4][3];
#pragma unroll
      for (int rg = 0; rg < 4; rg++)
#pragma unroll
        for (int k = 0; k < 3; k++) pk[rg][k] = 0.f;
#pragma unroll
      for (int nt = 0; nt < 4; nt++) {
        int col = w * 64 + nt * 16 + c;
#pragma unroll
        for (int rg = 0; rg < 4; rg++) {
          int row = mt * 16 + q * 4 + rg;
          float hv1 = fmaxf(acc[mt * 4 + nt][rg] + bias[nt], 0.f);
          float m0v = h2f(buf0[row * kPitch + col]);
#pragma unroll
          for (int k = 0; k < 3; k++)
            pk[rg][k] += m0v * w0v[nt][k] + hv1 * w1v[nt][k];
        }
      }
#pragma unroll
      for (int s = 1; s < 16; s <<= 1)
#pragma unroll
        for (int rg = 0; rg < 4; rg++)
#pragma unroll
          for (int k = 0; k < 3; k++)
            pk[rg][k] += __shfl_xor(pk[rg][k], s, 64);
      if (c == 0) {
#pragma unroll
        for (int rg = 0; rg < 4; rg++) {
          int row = mt * 16 + q * 4 + rg;
#pragma unroll
          for (int k = 0; k < 3; k++)
            scratch[row * 12 + k * 4 + w] = pk[rg][k];
        }
      }
    }
  }
  __syncthreads();

  if (tid < 192) {
    int row = tid / 3, k = tid % 3;
    int b = row >> 4, px = px0 + (row & 15);
    float s = outb0[k] + outb1[k];
#pragma unroll
    for (int ww = 0; ww < 4; ww++) s += scratch[row * 12 + k * 4 + ww];
    dout[((size_t)b * kHW + px) * 3 + k] = s;
  }
}

// ---------------- launch ----------------
extern "C" void kernel_launch(void* const* d_in, const int* in_sizes, int n_in,
                              void* d_out, int out_size, void* d_ws, size_t ws_size,
                              hipStream_t stream) {
  const float* coords = (const float*)d_in[0];
  const float* tokens = (const float*)d_in[1];
  const float* Bq     = (const float*)d_in[2];
  const float* Bl0    = (const float*)d_in[3];
  const float* Bl1    = (const float*)d_in[4];
  const float* qW     = (const float*)d_in[5];
  const float* qb     = (const float*)d_in[6];
  const float* toqW   = (const float*)d_in[7];
  const float* tokvW  = (const float*)d_in[8];
  const float* tooW   = (const float*)d_in[9];
  const float* toob   = (const float*)d_in[10];
  const float* bwW0   = (const float*)d_in[11];
  const float* bwb0   = (const float*)d_in[12];
  const float* bwW1   = (const float*)d_in[13];
  const float* bwb1   = (const float*)d_in[14];
  const float* modW0  = (const float*)d_in[15];
  const float* modb0  = (const float*)d_in[16];
  const float* modW1  = (const float*)d_in[17];
  const float* modb1  = (const float*)d_in[18];
  const float* hvW0   = (const float*)d_in[19];
  const float* hvb0   = (const float*)d_in[20];
  const float* outW0  = (const float*)d_in[21];
  const float* outb0  = (const float*)d_in[22];
  const float* outW1  = (const float*)d_in[23];
  const float* outb1  = (const float*)d_in[24];

  char* ws = (char*)d_ws;
  float*          t_ws   = (float*)(ws + 0);                  //   64 KB
  unsigned short* qc_ws  = (unsigned short*)(ws + 65536);     //    4 MB
  unsigned short* h0_hf  = (unsigned short*)(ws + 4259840);   //    8 MB
  unsigned short* h1_hf  = (unsigned short*)(ws + 12648448);  //    8 MB
  unsigned short* o_hf   = (unsigned short*)(ws + 21037056);  //   16 MB
  unsigned short* kn_ws  = (unsigned short*)(ws + 37814272);  //  256 KB
  unsigned short* vt_ws  = (unsigned short*)(ws + 38076416);  //  256 KB
  unsigned short* tooWt  = (unsigned short*)(ws + 38338560);  //   64 KB
  unsigned short* modW0t = (unsigned short*)(ws + 38404096);  //  128 KB
  unsigned short* modW1t = (unsigned short*)(ws + 38535168);  //  128 KB
  unsigned short* hvW0t  = (unsigned short*)(ws + 38666240);  //  128 KB
  unsigned short* qWt    = (unsigned short*)(ws + 38797312);  //   32 KB
  unsigned short* bw0t   = (unsigned short*)(ws + 38830080);  //   32 KB
  unsigned short* bw1t   = (unsigned short*)(ws + 38862848);  //   32 KB
  unsigned short* toqWt  = (unsigned short*)(ws + 38895616);  //   64 KB

  prep_kernel<<<dim3(kB * kM + 64), 256, 0, stream>>>(
      tokens, tokvW, kn_ws, vt_ws,
      tooW, modW0, modW1, hvW0, qW, bwW0, bwW1, toqW,
      tooWt, modW0t, modW1t, hvW0t, qWt, bw0t, bw1t, toqWt);
  feat_kernel<<<dim3(kHW / 32), 256, 0, stream>>>(
      coords, Bq, Bl0, Bl1, qb, bwb0, bwb1,
      qWt, bw0t, bw1t, toqWt,
      t_ws, qc_ws, h0_hf, h1_hf);
  attn_kernel<<<dim3(kHW / 32, kB), 256, 0, stream>>>(kn_ws, vt_ws, qc_ws, t_ws, o_hf);
  mlp_kernel<<<dim3(kHW / 16), 256, 0, stream>>>(
      o_hf, h0_hf, h1_hf, tooWt, toob, modW0t, modb0, modW1t, modb1,
      hvW0t, hvb0, outW0, outb0, outW1, outb1, (float*)d_out);
}

// Round 12
// 231.630 us; speedup vs baseline: 1.2384x; 1.0200x over previous
//
#include <hip/hip_runtime.h>
#include <stdint.h>

constexpr int kHW = 16384;   // 128*128 pixels (grid shared across batch)
constexpr int kB  = 4;
constexpr int kM  = 256;     // tokens

typedef _Float16 half8 __attribute__((ext_vector_type(8)));  // 8 fp16 (4 VGPRs)
typedef __attribute__((ext_vector_type(4))) float f32x4;     // MFMA accum

// ---------------- helpers ----------------
__device__ __forceinline__ unsigned short f2h(float f) {
  _Float16 h = (_Float16)f;
  return __builtin_bit_cast(unsigned short, h);
}
__device__ __forceinline__ float h2f(unsigned short u) {
  return (float)__builtin_bit_cast(_Float16, u);
}

// ---------------- kernel 0: prep = wprep (64 blocks) + kv (1024 blocks), one launch ----------------
__global__ __launch_bounds__(256) void prep_kernel(
    const float* __restrict__ tokens, const float* __restrict__ tokvW,
    unsigned short* __restrict__ kn_ws, unsigned short* __restrict__ vt_ws,
    const float* __restrict__ tooW, const float* __restrict__ modW0,
    const float* __restrict__ modW1, const float* __restrict__ hvW0,
    const float* __restrict__ qW, const float* __restrict__ bwW0,
    const float* __restrict__ bwW1, const float* __restrict__ toqW,
    unsigned short* __restrict__ tooWt, unsigned short* __restrict__ modW0t,
    unsigned short* __restrict__ modW1t, unsigned short* __restrict__ hvW0t,
    unsigned short* __restrict__ qWt, unsigned short* __restrict__ bw0t,
    unsigned short* __restrict__ bw1t, unsigned short* __restrict__ toqWt)
{
  __shared__ __align__(16) float tok[256];
  int bx = blockIdx.x, tid = threadIdx.x;

  if (bx < kB * kM) {
    // ---- kv part ----
    int b = bx >> 8, j = bx & 255, c = tid;
    tok[c] = tokens[(b * kM + j) * 256 + c];
    __syncthreads();
    float acc = 0.f;
    for (int i4 = 0; i4 < 64; i4++) {
      float4 t4 = *(const float4*)&tok[i4 * 4];
      acc += t4.x * tokvW[(i4*4+0)*256 + c] + t4.y * tokvW[(i4*4+1)*256 + c]
           + t4.z * tokvW[(i4*4+2)*256 + c] + t4.w * tokvW[(i4*4+3)*256 + c];
    }
    unsigned short hv = f2h(acc);
    if (c < 128) {
      int h = c >> 6, dd = c & 63;
      kn_ws[((size_t)(b*2+h)*256 + j) * 64 + dd] = hv;
    } else {
      int c2 = c - 128;
      int h = c2 >> 6, dd = c2 & 63;
      vt_ws[((size_t)(b*2+h)*64 + dd) * 256 + j] = hv;
    }
  } else {
    // ---- wprep part: block t -> (matrix m, K-chunk ch of 8) ----
    int t = bx - kB * kM;          // 0..63
    int m = t >> 3, ch = t & 7;
    const float* Ws[8] = {tooW, modW0, modW1, hvW0, qW, bwW0, bwW1, toqW};
    unsigned short* Wts[8] = {tooWt, modW0t, modW1t, hvW0t, qWt, bw0t, bw1t, toqWt};
    const int Ks[8] = {128, 256, 256, 256, 64, 64, 64, 256};
    const int Ns[8] = {256, 256, 256, 256, 256, 256, 256, 128};
    const float* W = Ws[m];
    unsigned short* Wt = Wts[m];
    int K = Ks[m], N = Ns[m];
    int nkb = K / 8;               // 8, 16 or 32
    int per = nkb >> 3;            // 1, 2 or 4 iters per block
    int kb0 = ch * per;
    if (tid < N) {
      for (int kb = kb0; kb < kb0 + per; kb++) {
        unsigned short sv[8];
#pragma unroll
        for (int i = 0; i < 8; i++)
          sv[i] = f2h(W[(kb * 8 + i) * N + tid]);   // coalesced across tid
        *(uint4*)&Wt[tid * K + kb * 8] = *(const uint4*)sv;
      }
    }
  }
}

// ---------------- kernel 2: MFMA per-pixel features (shared across batch) ----------------
// + cross-barrier first-step weight prefetch + bias prefetch + setprio.
constexpr int kFPitch = 72;    // fp16 pitch for ff rows (144 B = 9*16)
constexpr int kXPitch = 264;   // fp16 pitch for xq rows

__global__ __launch_bounds__(256, 2) void feat_kernel(
    const float* __restrict__ coords,
    const float* __restrict__ Bq, const float* __restrict__ Bl0, const float* __restrict__ Bl1,
    const float* __restrict__ qb, const float* __restrict__ bwb0, const float* __restrict__ bwb1,
    const unsigned short* __restrict__ qWt, const unsigned short* __restrict__ bw0t,
    const unsigned short* __restrict__ bw1t, const unsigned short* __restrict__ toqWt,
    float* __restrict__ t_ws, unsigned short* __restrict__ qc_ws,
    unsigned short* __restrict__ h0_hf, unsigned short* __restrict__ h1_hf)
{
  __shared__ __align__(16) unsigned short ff_s[3][32][kFPitch];
  __shared__ __align__(16) unsigned short xq_s[32][kXPitch];
  __shared__ float coords_s[64];

  int tid = threadIdx.x;
  int px0 = blockIdx.x * 32;
  int w = tid >> 6, ln = tid & 63;
  int c = ln & 15, q = ln >> 4;

  if (tid < 64) coords_s[tid] = coords[px0 * 2 + tid];
  __syncthreads();

  // prefetch mat0 (qWt) first K-step + all 3 biases -- hide under sincos
  half8 bpre[4];
#pragma unroll
  for (int nt = 0; nt < 4; nt++)
    bpre[nt] = *(const half8*)(qWt + (size_t)(w*64 + nt*16 + c) * 64 + q * 8);
  float bv0[4], bv1[4], bv2[4];
#pragma unroll
  for (int nt = 0; nt < 4; nt++) {
    int col = w*64 + nt*16 + c;
    bv0[nt] = qb[col];
    bv1[nt] = bwb0[col];
    bv2[nt] = bwb1[col];
  }

  // ---- Fourier features: 3 mats * 32 px * 64 f = 6144 vals, 24/thread ----
#pragma unroll
  for (int r = 0; r < 24; r++) {
    int v = r * 256 + tid;
    int mat = v >> 11;
    int p = (v >> 6) & 31;
    int f = v & 63;
    int fr = f & 31;
    const float* Bm = (mat == 0) ? Bq : (mat == 1 ? Bl0 : Bl1);
    float x = coords_s[p * 2 + 0];
    float y = coords_s[p * 2 + 1];
    float proj = 6.283185307179586f * (x * Bm[fr*2+0] + y * Bm[fr*2+1]);
    float s, cc;
    __sincosf(proj, &s, &cc);
    ff_s[mat][p][f] = f2h((f < 32) ? cc : s);
  }
  if (tid < 32) {
    float x = coords_s[tid * 2 + 0];
    float y = coords_s[tid * 2 + 1];
    int row = min(max((int)(x * 16.0f), 0), 15);
    int col = min(max((int)(y * 16.0f), 0), 15);
    t_ws[px0 + tid] = (float)(row * 16 + col) * (1.0f / 256.0f);
  }
  __syncthreads();

  const f32x4 zero4 = {0.f, 0.f, 0.f, 0.f};

  // ---- 3 GEMMs: M=32, N=256 (wave owns 64 cols), K=64 ----
#pragma unroll
  for (int mat = 0; mat < 3; mat++) {
    const unsigned short* Wt = (mat == 0) ? qWt : (mat == 1 ? bw0t : bw1t);
    f32x4 acc[8];
#pragma unroll
    for (int i = 0; i < 8; i++) acc[i] = zero4;
#pragma unroll
    for (int ks = 0; ks < 2; ks++) {
      int koff = ks * 32 + q * 8;
      half8 bfr[4];
      if (ks == 0) {
#pragma unroll
        for (int nt = 0; nt < 4; nt++) bfr[nt] = bpre[nt];
      } else {
#pragma unroll
        for (int nt = 0; nt < 4; nt++)
          bfr[nt] = *(const half8*)(Wt + (size_t)(w*64 + nt*16 + c) * 64 + koff);
      }
      half8 afr[2];
#pragma unroll
      for (int mt = 0; mt < 2; mt++)
        afr[mt] = *(const half8*)(&ff_s[mat][mt*16 + c][koff]);
      __builtin_amdgcn_s_setprio(1);
#pragma unroll
      for (int mt = 0; mt < 2; mt++)
#pragma unroll
        for (int nt = 0; nt < 4; nt++)
          acc[mt*4+nt] = __builtin_amdgcn_mfma_f32_16x16x32_f16(afr[mt], bfr[nt], acc[mt*4+nt], 0, 0, 0);
      __builtin_amdgcn_s_setprio(0);
    }
    // chain-prefetch next mat's first K-step (hides under this epilogue)
    if (mat == 0) {
#pragma unroll
      for (int nt = 0; nt < 4; nt++)
        bpre[nt] = *(const half8*)(bw0t + (size_t)(w*64 + nt*16 + c) * 64 + q * 8);
    } else if (mat == 1) {
#pragma unroll
      for (int nt = 0; nt < 4; nt++)
        bpre[nt] = *(const half8*)(bw1t + (size_t)(w*64 + nt*16 + c) * 64 + q * 8);
    }
#pragma unroll
    for (int mt = 0; mt < 2; mt++)
#pragma unroll
      for (int nt = 0; nt < 4; nt++)
#pragma unroll
        for (int rg = 0; rg < 4; rg++) {
          int row = mt*16 + q*4 + rg, col = w*64 + nt*16 + c;
          float bv = (mat == 0) ? bv0[nt] : (mat == 1 ? bv1[nt] : bv2[nt]);
          unsigned short hv = f2h(fmaxf(acc[mt*4+nt][rg] + bv, 0.f));
          if (mat == 0)      xq_s[row][col] = hv;
          else if (mat == 1) h0_hf[((size_t)(px0 + row)) * 256 + col] = hv;
          else               h1_hf[((size_t)(px0 + row)) * 256 + col] = hv;
        }
  }
  // prefetch q-GEMM (toqWt) first K-step before the barrier
  half8 qpre[2];
#pragma unroll
  for (int nt = 0; nt < 2; nt++)
    qpre[nt] = *(const half8*)(toqWt + (size_t)(w*32 + nt*16 + c) * 256 + q * 8);
  __syncthreads();   // xq_s ready

  // ---- q GEMM: M=32, N=128 (wave owns 32 cols), K=256, no bias ----
  {
    f32x4 acc2[4];
#pragma unroll
    for (int i = 0; i < 4; i++) acc2[i] = zero4;
#pragma unroll
    for (int kt = 0; kt < 8; kt++) {
      int koff = kt * 32 + q * 8;
      half8 bfr[2];
      if (kt == 0) {
#pragma unroll
        for (int nt = 0; nt < 2; nt++) bfr[nt] = qpre[nt];
      } else {
#pragma unroll
        for (int nt = 0; nt < 2; nt++)
          bfr[nt] = *(const half8*)(toqWt + (size_t)(w*32 + nt*16 + c) * 256 + koff);
      }
      half8 afr[2];
#pragma unroll
      for (int mt = 0; mt < 2; mt++)
        afr[mt] = *(const half8*)(&xq_s[mt*16 + c][koff]);
      __builtin_amdgcn_s_setprio(1);
#pragma unroll
      for (int mt = 0; mt < 2; mt++)
#pragma unroll
        for (int nt = 0; nt < 2; nt++)
          acc2[mt*2+nt] = __builtin_amdgcn_mfma_f32_16x16x32_f16(afr[mt], bfr[nt], acc2[mt*2+nt], 0, 0, 0);
      __builtin_amdgcn_s_setprio(0);
    }
#pragma unroll
    for (int mt = 0; mt < 2; mt++)
#pragma unroll
      for (int nt = 0; nt < 2; nt++)
#pragma unroll
        for (int rg = 0; rg < 4; rg++) {
          int row = mt*16 + q*4 + rg, col = w*32 + nt*16 + c;
          qc_ws[((size_t)(px0 + row)) * 128 + col] = f2h(acc2[mt*2+nt][rg]);
        }
  }
}

// ---------------- kernel 3: MFMA cross attention with spatial bias (fp16) ----------------
// + K/V first-step prefetch + setprio; per-iteration loop-top barrier replaced
// by ONE pre-loop barrier (P_s/red_max/red_sum WAR ordered by the two inner
// barriers + program order -- see R12 ledger analysis).
constexpr int kPPitch = 264;

__global__ __launch_bounds__(256, 2) void attn_kernel(
    const unsigned short* __restrict__ kn_ws,
    const unsigned short* __restrict__ vt_ws,
    const unsigned short* __restrict__ qc_ws,
    const float* __restrict__ t_ws,
    unsigned short* __restrict__ o_hf)
{
  __shared__ __align__(16) unsigned short P_s[32 * kPPitch];
  __shared__ float t_s[32];
  __shared__ float red_max[32][4];
  __shared__ float red_sum[32][4];

  int b = blockIdx.y;
  int px0 = blockIdx.x * 32;
  int tid = threadIdx.x;
  int w = tid >> 6, ln = tid & 63;
  int c = ln & 15, q = ln >> 4;

  if (tid < 32) t_s[tid] = t_ws[px0 + tid];

  const f32x4 zero4 = {0.f, 0.f, 0.f, 0.f};

  // prefetch h=0's K first-step
  half8 kpre[4];
  {
    const unsigned short* kb = kn_ws + (size_t)(b*2) * 256 * 64;
#pragma unroll
    for (int nt = 0; nt < 4; nt++)
      kpre[nt] = *(const half8*)(kb + (size_t)(w*64 + nt*16 + c) * 64 + q * 8);
  }
  __syncthreads();   // single ordering point: t_s visible to all waves

#pragma unroll
  for (int h = 0; h < 2; h++) {
    // ---- QK^T: M=32, N=256 (wave strip of 64), K=64 ----
    f32x4 acc[8];
#pragma unroll
    for (int i = 0; i < 8; i++) acc[i] = zero4;
    const unsigned short* kbase = kn_ws + (size_t)(b*2+h) * 256 * 64;
#pragma unroll
    for (int ks = 0; ks < 2; ks++) {
      int koff = ks * 32 + q * 8;
      half8 a0 = *(const half8*)(qc_ws + (size_t)(px0 + c) * 128 + h*64 + koff);
      half8 a1 = *(const half8*)(qc_ws + (size_t)(px0 + 16 + c) * 128 + h*64 + koff);
      half8 bf[4];
      if (ks == 0) {
#pragma unroll
        for (int nt = 0; nt < 4; nt++) bf[nt] = kpre[nt];
      } else {
#pragma unroll
        for (int nt = 0; nt < 4; nt++)
          bf[nt] = *(const half8*)(kbase + (size_t)(w*64 + nt*16 + c) * 64 + koff);
      }
      __builtin_amdgcn_s_setprio(1);
#pragma unroll
      for (int nt = 0; nt < 4; nt++) {
        acc[0*4+nt] = __builtin_amdgcn_mfma_f32_16x16x32_f16(a0, bf[nt], acc[0*4+nt], 0, 0, 0);
        acc[1*4+nt] = __builtin_amdgcn_mfma_f32_16x16x32_f16(a1, bf[nt], acc[1*4+nt], 0, 0, 0);
      }
      __builtin_amdgcn_s_setprio(0);
    }

    // prefetch V first-step (hides under softmax + 2 barriers)
    const unsigned short* vbase = vt_ws + (size_t)(b*2+h) * 64 * 256;
    half8 vpre = *(const half8*)(vbase + (size_t)(w*16 + c) * 256 + q * 8);

    // ---- bias + scale, per-lane row max ----
    float lm[2][4];
#pragma unroll
    for (int mt = 0; mt < 2; mt++)
#pragma unroll
      for (int rg = 0; rg < 4; rg++) {
        int row = mt*16 + q*4 + rg;
        float tv = t_s[row];
        float mx = -1e30f;
#pragma unroll
        for (int nt = 0; nt < 4; nt++) {
          int token = w*64 + nt*16 + c;
          float pos = ((float)token + 0.5f) * (1.0f / 256.0f);
          float db = tv - pos;
          float sb = acc[mt*4+nt][rg] * 0.125f - 10.0f * db * db;
          acc[mt*4+nt][rg] = sb;
          mx = fmaxf(mx, sb);
        }
        lm[mt][rg] = mx;
      }
#pragma unroll
    for (int s = 1; s < 16; s <<= 1)
#pragma unroll
      for (int mt = 0; mt < 2; mt++)
#pragma unroll
        for (int rg = 0; rg < 4; rg++)
          lm[mt][rg] = fmaxf(lm[mt][rg], __shfl_xor(lm[mt][rg], s, 64));
    if (c == 0) {
#pragma unroll
      for (int mt = 0; mt < 2; mt++)
#pragma unroll
        for (int rg = 0; rg < 4; rg++)
          red_max[mt*16 + q*4 + rg][w] = lm[mt][rg];
    }
    __syncthreads();   // barrier 1: red_max ready (also orders prev-iter P_s reads before this iter's P_s writes)

    // ---- exp, P_s write, partial row sums ----
    float ps[2][4];
#pragma unroll
    for (int mt = 0; mt < 2; mt++)
#pragma unroll
      for (int rg = 0; rg < 4; rg++) {
        int row = mt*16 + q*4 + rg;
        float gm = fmaxf(fmaxf(red_max[row][0], red_max[row][1]),
                         fmaxf(red_max[row][2], red_max[row][3]));
        float sum = 0.f;
#pragma unroll
        for (int nt = 0; nt < 4; nt++) {
          float e = __expf(acc[mt*4+nt][rg] - gm);
          sum += e;
          P_s[row * kPPitch + w*64 + nt*16 + c] = f2h(e);
        }
        ps[mt][rg] = sum;
      }
#pragma unroll
    for (int s = 1; s < 16; s <<= 1)
#pragma unroll
      for (int mt = 0; mt < 2; mt++)
#pragma unroll
        for (int rg = 0; rg < 4; rg++)
          ps[mt][rg] += __shfl_xor(ps[mt][rg], s, 64);
    if (c == 0) {
#pragma unroll
      for (int mt = 0; mt < 2; mt++)
#pragma unroll
        for (int rg = 0; rg < 4; rg++)
          red_sum[mt*16 + q*4 + rg][w] = ps[mt][rg];
    }
    __syncthreads();   // barrier 2: P_s + red_sum ready

    // ---- PV: wave w -> dh cols [w*16, w*16+16), K=256 ----
    f32x4 oacc[2] = {zero4, zero4};
#pragma unroll
    for (int kt = 0; kt < 8; kt++) {
      int koff = kt * 32 + q * 8;
      half8 bf = (kt == 0) ? vpre
               : *(const half8*)(vbase + (size_t)(w*16 + c) * 256 + koff);
      half8 a0 = *(const half8*)(P_s + (0*16 + c) * kPPitch + koff);
      half8 a1 = *(const half8*)(P_s + (1*16 + c) * kPPitch + koff);
      __builtin_amdgcn_s_setprio(1);
      oacc[0] = __builtin_amdgcn_mfma_f32_16x16x32_f16(a0, bf, oacc[0], 0, 0, 0);
      oacc[1] = __builtin_amdgcn_mfma_f32_16x16x32_f16(a1, bf, oacc[1], 0, 0, 0);
      __builtin_amdgcn_s_setprio(0);
    }
    // prefetch h=1's K first-step during this epilogue
    if (h == 0) {
      const unsigned short* kb1 = kn_ws + (size_t)(b*2+1) * 256 * 64;
#pragma unroll
      for (int nt = 0; nt < 4; nt++)
        kpre[nt] = *(const half8*)(kb1 + (size_t)(w*64 + nt*16 + c) * 64 + q * 8);
    }
#pragma unroll
    for (int mt = 0; mt < 2; mt++)
#pragma unroll
      for (int rg = 0; rg < 4; rg++) {
        int row = mt*16 + q*4 + rg;
        float rinv = 1.0f / (red_sum[row][0] + red_sum[row][1] +
                             red_sum[row][2] + red_sum[row][3]);
        o_hf[((size_t)(b * kHW + px0 + row)) * 128 + h*64 + w*16 + c] =
            f2h(oacc[mt][rg] * rinv);
      }
  }
}

// ---------------- kernel 4: MFMA MLP chain (R10 + entry bias prefetch) ----------------
constexpr int kPitch = 264;   // fp16 LDS pitch

template <int KD>
__device__ __forceinline__ void prefetchB(
    const unsigned short* wt, int c, int q, half8 pre[4])
{
#pragma unroll
  for (int nt = 0; nt < 4; nt++)
    pre[nt] = *(const half8*)(wt + (nt * 16 + c) * KD + q * 8);
}

template <int KD>
__device__ __forceinline__ void gemm4p(
    const unsigned short* abuf, const unsigned short* wt,
    f32x4* acc /*[4*4]*/, int c, int q, const half8 pre[4])
{
#pragma unroll
  for (int ks = 0; ks < KD / 32; ks++) {
    int koff = ks * 32 + q * 8;
    half8 bfr[4];
    if (ks == 0) {
#pragma unroll
      for (int nt = 0; nt < 4; nt++) bfr[nt] = pre[nt];
    } else {
#pragma unroll
      for (int nt = 0; nt < 4; nt++)
        bfr[nt] = *(const half8*)(wt + (nt * 16 + c) * KD + koff);
    }
    half8 afr[4];
#pragma unroll
    for (int mt = 0; mt < 4; mt++)
      afr[mt] = *(const half8*)(abuf + (mt * 16 + c) * kPitch + koff);
    __builtin_amdgcn_s_setprio(1);
#pragma unroll
    for (int mt = 0; mt < 4; mt++)
#pragma unroll
      for (int nt = 0; nt < 4; nt++)
        acc[mt * 4 + nt] = __builtin_amdgcn_mfma_f32_16x16x32_f16(afr[mt], bfr[nt], acc[mt * 4 + nt], 0, 0, 0);
    __builtin_amdgcn_s_setprio(0);
  }
}

__global__ __launch_bounds__(256, 2) void mlp_kernel(
    const unsigned short* __restrict__ o_hf,
    const unsigned short* __restrict__ h0_hf, const unsigned short* __restrict__ h1_hf,
    const unsigned short* __restrict__ tooWt, const float* __restrict__ toob,
    const unsigned short* __restrict__ modW0t, const float* __restrict__ modb0,
    const unsigned short* __restrict__ modW1t, const float* __restrict__ modb1,
    const unsigned short* __restrict__ hvW0t, const float* __restrict__ hvb0,
    const float* __restrict__ outW0, const float* __restrict__ outb0,
    const float* __restrict__ outW1, const float* __restrict__ outb1,
    float* __restrict__ dout)
{
  __shared__ __align__(16) unsigned short buf0[64 * kPitch];  // o, then m0 (hv0)
  __shared__ __align__(16) unsigned short buf1[64 * kPitch];  // mod, then S
  __shared__ __align__(16) unsigned short hbuf[16 * kPitch];  // h0, then h1 (per-pixel)
  __shared__ __align__(16) float scratch[64 * 3 * 4];         // out partials [row][k][wave]

  int tid = threadIdx.x;
  int px0 = blockIdx.x * 16;
  int w = tid >> 6, ln = tid & 63;
  int c = ln & 15, q = ln >> 4;

  const unsigned short* wt1 = tooWt  + (size_t)w * 64 * 128;
  const unsigned short* wt2 = modW0t + (size_t)w * 64 * 256;
  const unsigned short* wt3 = modW1t + (size_t)w * 64 * 256;
  const unsigned short* wt4 = hvW0t  + (size_t)w * 64 * 256;

  // prefetch P1's first B-step + ALL phase biases before staging
  half8 pre[4];
  prefetchB<128>(wt1, c, q, pre);
  float b1v[4], b2v[4], b3v[4], b4v[4];
#pragma unroll
  for (int nt = 0; nt < 4; nt++) {
    int col = w * 64 + nt * 16 + c;
    b1v[nt] = toob[col];
    b2v[nt] = modb0[col];
    b3v[nt] = modb1[col];
    b4v[nt] = hvb0[col];
  }

  // ---- stage o (64 rows x 128) and h0 (16 px x 256) ----
#pragma unroll
  for (int i = 0; i < 4; i++) {
    int idx = i * 256 + tid;              // 1024 x uint4 (8 fp16)
    int r = idx >> 4, c8 = (idx & 15) * 8;
    int b = r >> 4, px = r & 15;
    uint4 v = *(const uint4*)(o_hf + ((size_t)(b * kHW + px0 + px)) * 128 + c8);
    *(uint4*)&buf0[r * kPitch + c8] = v;
  }
#pragma unroll
  for (int i = 0; i < 2; i++) {
    int idx = i * 256 + tid;              // 512 x uint4
    int p = idx >> 5, c8 = (idx & 31) * 8;
    uint4 v = *(const uint4*)(h0_hf + ((size_t)(px0 + p)) * 256 + c8);
    *(uint4*)&hbuf[p * kPitch + c8] = v;
  }
  __syncthreads();

  f32x4 acc[16];
  const f32x4 zero4 = {0.f, 0.f, 0.f, 0.f};

  // ---- P1: mod = o @ tooW + toob -> buf1 ----
#pragma unroll
  for (int i = 0; i < 16; i++) acc[i] = zero4;
  gemm4p<128>(buf0, wt1, acc, c, q, pre);
  prefetchB<256>(wt2, c, q, pre);   // P2 weights: load during P1 epilogue
  {
#pragma unroll
    for (int mt = 0; mt < 4; mt++)
#pragma unroll
      for (int nt = 0; nt < 4; nt++)
#pragma unroll
        for (int rg = 0; rg < 4; rg++) {
          int row = mt * 16 + q * 4 + rg, col = w * 64 + nt * 16 + c;
          buf1[row * kPitch + col] = f2h(acc[mt * 4 + nt][rg] + b1v[nt]);
        }
  }
  __syncthreads();   // barrier A: mod ready; all o reads done

  // ---- P2: m0 = relu(h0 + mod @ modW0 + b) -> buf0 ----
#pragma unroll
  for (int i = 0; i < 16; i++) acc[i] = zero4;
  gemm4p<256>(buf1, wt2, acc, c, q, pre);
  prefetchB<256>(wt3, c, q, pre);   // P3 weights
  {
    float hr[4][4];
#pragma unroll
    for (int nt = 0; nt < 4; nt++) {
      int col = w * 64 + nt * 16 + c;
#pragma unroll
      for (int rg = 0; rg < 4; rg++)
        hr[nt][rg] = h2f(hbuf[(q * 4 + rg) * kPitch + col]);
    }
#pragma unroll
    for (int mt = 0; mt < 4; mt++)
#pragma unroll
      for (int nt = 0; nt < 4; nt++)
#pragma unroll
        for (int rg = 0; rg < 4; rg++) {
          int row = mt * 16 + q * 4 + rg, col = w * 64 + nt * 16 + c;
          buf0[row * kPitch + col] =
              f2h(fmaxf(acc[mt * 4 + nt][rg] + b2v[nt] + hr[nt][rg], 0.f));
        }
  }
  __syncthreads();   // barrier B: h0 consumed, m0 in buf0

  // ---- P3: stage h1; m1 = relu(h1 + mod @ modW1 + b); S = m0 + m1 -> buf1 ----
#pragma unroll
  for (int i = 0; i < 2; i++) {
    int idx = i * 256 + tid;
    int p = idx >> 5, c8 = (idx & 31) * 8;
    uint4 v = *(const uint4*)(h1_hf + ((size_t)(px0 + p)) * 256 + c8);
    *(uint4*)&hbuf[p * kPitch + c8] = v;
  }
#pragma unroll
  for (int i = 0; i < 16; i++) acc[i] = zero4;
  gemm4p<256>(buf1, wt3, acc, c, q, pre);
  prefetchB<256>(wt4, c, q, pre);   // P4 weights
  __syncthreads();   // barrier C: h1 staged AND all mod reads done
  {
    float hr[4][4];
#pragma unroll
    for (int nt = 0; nt < 4; nt++) {
      int col = w * 64 + nt * 16 + c;
#pragma unroll
      for (int rg = 0; rg < 4; rg++)
        hr[nt][rg] = h2f(hbuf[(q * 4 + rg) * kPitch + col]);
    }
#pragma unroll
    for (int mt = 0; mt < 4; mt++)
#pragma unroll
      for (int nt = 0; nt < 4; nt++)
#pragma unroll
        for (int rg = 0; rg < 4; rg++) {
          int row = mt * 16 + q * 4 + rg, col = w * 64 + nt * 16 + c;
          float m0v = h2f(buf0[row * kPitch + col]);
          float v = m0v + fmaxf(acc[mt * 4 + nt][rg] + b3v[nt] + hr[nt][rg], 0.f);
          buf1[row * kPitch + col] = f2h(v);
        }
  }
  __syncthreads();   // barrier D: S ready

  // ---- P4: hv1 = relu(S @ hvW0 + b); fused out epilogue ----
#pragma unroll
  for (int i = 0; i < 16; i++) acc[i] = zero4;
  gemm4p<256>(buf1, wt4, acc, c, q, pre);
  {
    float w0v[4][3], w1v[4][3];
#pragma unroll
    for (int nt = 0; nt < 4; nt++) {
      int col = w * 64 + nt * 16 + c;
#pragma unroll
      for (int k = 0; k < 3; k++) {
        w0v[nt][k] = outW0[col * 3 + k];
        w1v[nt][k] = outW1[col * 3 + k];
      }
    }
#pragma unroll
    for (int mt = 0; mt < 4; mt++) {
      float pk[4][3];
#pragma unroll
      for (int rg = 0; rg < 4; rg++)
#pragma unroll
        for (int k = 0; k < 3; k++) pk[rg][k] = 0.f;
#pragma unroll
      for (int nt = 0; nt < 4; nt++) {
        int col = w * 64 + nt * 16 + c;
#pragma unroll
        for (int rg = 0; rg < 4; rg++) {
          int row = mt * 16 + q * 4 + rg;
          float hv1 = fmaxf(acc[mt * 4 + nt][rg] + b4v[nt], 0.f);
          float m0v = h2f(buf0[row * kPitch + col]);
#pragma unroll
          for (int k = 0; k < 3; k++)
            pk[rg][k] += m0v * w0v[nt][k] + hv1 * w1v[nt][k];
        }
      }
#pragma unroll
      for (int s = 1; s < 16; s <<= 1)
#pragma unroll
        for (int rg = 0; rg < 4; rg++)
#pragma unroll
          for (int k = 0; k < 3; k++)
            pk[rg][k] += __shfl_xor(pk[rg][k], s, 64);
      if (c == 0) {
#pragma unroll
        for (int rg = 0; rg < 4; rg++) {
          int row = mt * 16 + q * 4 + rg;
#pragma unroll
          for (int k = 0; k < 3; k++)
            scratch[row * 12 + k * 4 + w] = pk[rg][k];
        }
      }
    }
  }
  __syncthreads();

  if (tid < 192) {
    int row = tid / 3, k = tid % 3;
    int b = row >> 4, px = px0 + (row & 15);
    float s = outb0[k] + outb1[k];
#pragma unroll
    for (int ww = 0; ww < 4; ww++) s += scratch[row * 12 + k * 4 + ww];
    dout[((size_t)b * kHW + px) * 3 + k] = s;
  }
}

// ---------------- launch ----------------
extern "C" void kernel_launch(void* const* d_in, const int* in_sizes, int n_in,
                              void* d_out, int out_size, void* d_ws, size_t ws_size,
                              hipStream_t stream) {
  const float* coords = (const float*)d_in[0];
  const float* tokens = (const float*)d_in[1];
  const float* Bq     = (const float*)d_in[2];
  const float* Bl0    = (const float*)d_in[3];
  const float* Bl1    = (const float*)d_in[4];
  const float* qW     = (const float*)d_in[5];
  const float* qb     = (const float*)d_in[6];
  const float* toqW   = (const float*)d_in[7];
  const float* tokvW  = (const float*)d_in[8];
  const float* tooW   = (const float*)d_in[9];
  const float* toob   = (const float*)d_in[10];
  const float* bwW0   = (const float*)d_in[11];
  const float* bwb0   = (const float*)d_in[12];
  const float* bwW1   = (const float*)d_in[13];
  const float* bwb1   = (const float*)d_in[14];
  const float* modW0  = (const float*)d_in[15];
  const float* modb0  = (const float*)d_in[16];
  const float* modW1  = (const float*)d_in[17];
  const float* modb1  = (const float*)d_in[18];
  const float* hvW0   = (const float*)d_in[19];
  const float* hvb0   = (const float*)d_in[20];
  const float* outW0  = (const float*)d_in[21];
  const float* outb0  = (const float*)d_in[22];
  const float* outW1  = (const float*)d_in[23];
  const float* outb1  = (const float*)d_in[24];

  char* ws = (char*)d_ws;
  float*          t_ws   = (float*)(ws + 0);                  //   64 KB
  unsigned short* qc_ws  = (unsigned short*)(ws + 65536);     //    4 MB
  unsigned short* h0_hf  = (unsigned short*)(ws + 4259840);   //    8 MB
  unsigned short* h1_hf  = (unsigned short*)(ws + 12648448);  //    8 MB
  unsigned short* o_hf   = (unsigned short*)(ws + 21037056);  //   16 MB
  unsigned short* kn_ws  = (unsigned short*)(ws + 37814272);  //  256 KB
  unsigned short* vt_ws  = (unsigned short*)(ws + 38076416);  //  256 KB
  unsigned short* tooWt  = (unsigned short*)(ws + 38338560);  //   64 KB
  unsigned short* modW0t = (unsigned short*)(ws + 38404096);  //  128 KB
  unsigned short* modW1t = (unsigned short*)(ws + 38535168);  //  128 KB
  unsigned short* hvW0t  = (unsigned short*)(ws + 38666240);  //  128 KB
  unsigned short* qWt    = (unsigned short*)(ws + 38797312);  //   32 KB
  unsigned short* bw0t   = (unsigned short*)(ws + 38830080);  //   32 KB
  unsigned short* bw1t   = (unsigned short*)(ws + 38862848);  //   32 KB
  unsigned short* toqWt  = (unsigned short*)(ws + 38895616);  //   64 KB

  prep_kernel<<<dim3(kB * kM + 64), 256, 0, stream>>>(
      tokens, tokvW, kn_ws, vt_ws,
      tooW, modW0, modW1, hvW0, qW, bwW0, bwW1, toqW,
      tooWt, modW0t, modW1t, hvW0t, qWt, bw0t, bw1t, toqWt);
  feat_kernel<<<dim3(kHW / 32), 256, 0, stream>>>(
      coords, Bq, Bl0, Bl1, qb, bwb0, bwb1,
      qWt, bw0t, bw1t, toqWt,
      t_ws, qc_ws, h0_hf, h1_hf);
  attn_kernel<<<dim3(kHW / 32, kB), 256, 0, stream>>>(kn_ws, vt_ws, qc_ws, t_ws, o_hf);
  mlp_kernel<<<dim3(kHW / 16), 256, 0, stream>>>(
      o_hf, h0_hf, h1_hf, tooWt, toob, modW0t, modb0, modW1t, modb1,
      hvW0t, hvb0, outW0, outb0, outW1, outb1, (float*)d_out);
}